// Round 2
// baseline (1388.908 us; speedup 1.0000x reference)
//
#include <hip/hip_runtime.h>

#define TT 32768   // B*S tokens
#define DD 512
#define HH 2048
#define EE 8
#define CAP 8192   // per-expert per-rank slot capacity (mean 4096, +68 sigma headroom)

typedef unsigned short u16;
typedef unsigned int u32;
typedef unsigned long long u64;
using short8  = __attribute__((ext_vector_type(8))) short;
using floatx4 = __attribute__((ext_vector_type(4))) float;

__device__ __forceinline__ u16 f2bf(float f) {
  unsigned u = __float_as_uint(f);
  u += 0x7FFFu + ((u >> 16) & 1u);   // RNE; inputs are finite
  return (u16)(u >> 16);
}

// async global->LDS, 16B per lane; lds dest is wave-uniform base + lane*16
__device__ __forceinline__ void gl2lds16(const u16* g, char* l) {
  __builtin_amdgcn_global_load_lds(
      (const __attribute__((address_space(1))) u32*)(const void*)g,
      (__attribute__((address_space(3))) u32*)(void*)l, 16, 0, 0);
}

// ------------- transpose fp32 [E][R][C] -> bf16 [E][C][R] -------------
__global__ void transpose_bf16(const float* __restrict__ in, u16* __restrict__ out, int R, int C) {
  __shared__ float tile[32][33];
  int e = blockIdx.z;
  const float* src = in + (size_t)e * R * C;
  u16* dst = out + (size_t)e * R * C;
  int tx = threadIdx.x, ty = threadIdx.y;
  int c0 = blockIdx.x * 32, r0 = blockIdx.y * 32;
#pragma unroll
  for (int i = 0; i < 32; i += 8)
    tile[ty + i][tx] = src[(size_t)(r0 + ty + i) * C + c0 + tx];
  __syncthreads();
#pragma unroll
  for (int i = 0; i < 32; i += 8)
    dst[(size_t)(c0 + ty + i) * R + r0 + tx] = f2bf(tile[tx][ty + i]);
}

// ------- router: one wave per token; fused bf16-x emit + rank-binned lists -------
// rank A = top-1 slot of each token, rank B = top-2 slot. Exactly one slot per
// token per rank => downstream out-writes are race-free without atomics.
__global__ void router_topk(const float* __restrict__ x, const float* __restrict__ noise,
                            const float* __restrict__ Wg, const float* __restrict__ bg,
                            const float* __restrict__ Wn, const float* __restrict__ bn,
                            u16* __restrict__ xb,
                            int* __restrict__ countsA, int* __restrict__ countsB,
                            int* __restrict__ listsA, int* __restrict__ listsB,
                            float* __restrict__ gatesA, float* __restrict__ gatesB) {
  const int t = (blockIdx.x * blockDim.x + threadIdx.x) >> 6;
  const int lane = threadIdx.x & 63;
  if (t >= TT) return;
  const float4* xr = (const float4*)(x + (size_t)t * DD) + lane * 2;
  float4 xa = xr[0], xbv = xr[1];
  float xv[8] = {xa.x, xa.y, xa.z, xa.w, xbv.x, xbv.y, xbv.z, xbv.w};
  // fused fp32->bf16 convert of x (wave already holds the whole row)
  {
    ushort4 o0, o1;
    o0.x = f2bf(xa.x); o0.y = f2bf(xa.y); o0.z = f2bf(xa.z); o0.w = f2bf(xa.w);
    o1.x = f2bf(xbv.x); o1.y = f2bf(xbv.y); o1.z = f2bf(xbv.z); o1.w = f2bf(xbv.w);
    ushort4* xo = (ushort4*)(xb + (size_t)t * DD) + lane * 2;
    xo[0] = o0; xo[1] = o1;
  }
  float pg[8], pn[8];
#pragma unroll
  for (int e = 0; e < 8; ++e) { pg[e] = 0.f; pn[e] = 0.f; }
  const float4* wg4 = (const float4*)(Wg + lane * 64);
  const float4* wn4 = (const float4*)(Wn + lane * 64);
#pragma unroll
  for (int j = 0; j < 8; ++j) {
    float xj = xv[j];
    float4 a = wg4[2 * j], b = wg4[2 * j + 1];
    pg[0] += xj * a.x; pg[1] += xj * a.y; pg[2] += xj * a.z; pg[3] += xj * a.w;
    pg[4] += xj * b.x; pg[5] += xj * b.y; pg[6] += xj * b.z; pg[7] += xj * b.w;
    a = wn4[2 * j]; b = wn4[2 * j + 1];
    pn[0] += xj * a.x; pn[1] += xj * a.y; pn[2] += xj * a.z; pn[3] += xj * a.w;
    pn[4] += xj * b.x; pn[5] += xj * b.y; pn[6] += xj * b.z; pn[7] += xj * b.w;
  }
#pragma unroll
  for (int off = 32; off; off >>= 1) {
#pragma unroll
    for (int e = 0; e < 8; ++e) {
      pg[e] += __shfl_xor(pg[e], off);
      pn[e] += __shfl_xor(pn[e], off);
    }
  }
  if (lane == 0) {
    float noisy[8];
#pragma unroll
    for (int e = 0; e < 8; ++e) {
      float nl = pn[e] + bn[e];
      float sp = (nl > 20.f) ? nl : log1pf(expf(nl));
      noisy[e] = pg[e] + bg[e] + noise[(size_t)t * EE + e] * sp;
    }
    int i0 = 0; float v0 = noisy[0];
#pragma unroll
    for (int e = 1; e < 8; ++e) if (noisy[e] > v0) { v0 = noisy[e]; i0 = e; }
    int i1 = -1; float v1 = -3.4e38f;
#pragma unroll
    for (int e = 0; e < 8; ++e) if (e != i0 && noisy[e] > v1) { v1 = noisy[e]; i1 = e; }
    float ed = expf(v1 - v0);
    float inv = 1.f / (1.f + ed);
    int s0 = atomicAdd(&countsA[i0], 1);
    int s1 = atomicAdd(&countsB[i1], 1);
    if (s0 < CAP) { listsA[i0 * CAP + s0] = t; gatesA[i0 * CAP + s0] = inv; }
    if (s1 < CAP) { listsB[i1 * CAP + s1] = t; gatesB[i1 * CAP + s1] = ed * inv; }
  }
}

// ============ PASS 1: H = relu(X_gathered @ W1 + b1)  (bf16, full 2048-wide) ============
// 128x128 tile, BK=64, 4 waves x (64x64), XOR-swizzled 16B LDS chunks.
// blockIdx.x = e + 8*(nt + 16*ms): expert in low bits pins the expert to one XCD
// (grid.x % 8 == 0); all 16 ntile-blocks of an (e, ms) pair are co-resident on that
// XCD so they share the same X m-tile through L2 (fetch X once, reuse 16x).
#define MS1 6
#define MS2 16
__global__ __launch_bounds__(256, 2)
void pass1_gemm(const u16* __restrict__ xb, const u16* __restrict__ w1t,
                const float* __restrict__ b1, const int* __restrict__ counts,
                const int* __restrict__ lists, u16* __restrict__ H) {
  __shared__ __align__(16) char lds[32768];
  char* ldsA = lds;           // W1^T tile [128 h][64 k]
  char* ldsB = lds + 16384;   // X tile    [128 m][64 k]
  const int e = blockIdx.x & 7;
  const int nt = (blockIdx.x >> 3) & 15;   // h-tile 0..15
  const int ms = blockIdx.x >> 7;          // m-seed 0..MS1-1
  int cnt = counts[e]; if (cnt > CAP) cnt = CAP;
  int eOff = 0;
#pragma unroll
  for (int j = 0; j < EE; ++j) {
    int cj = counts[j]; if (cj > CAP) cj = CAP;
    eOff += (j < e) ? cj : 0;
  }
  const int tid = threadIdx.x, lane = tid & 63, w = tid >> 6;
  const int col16 = lane & 15, quad = lane >> 4;
  const int hh = w & 1, mh = w >> 1;

  int rowi[4], kqi[4];
  const u16* wptr[4];
#pragma unroll
  for (int i = 0; i < 4; ++i) {
    int c = tid + i * 256;
    rowi[i] = c >> 3;
    kqi[i] = (c & 7) ^ (rowi[i] & 7);
    wptr[i] = w1t + (size_t)(e * HH + nt * 128 + rowi[i]) * DD + kqi[i] * 8;
  }

  for (int mtile = ms; mtile * 128 < cnt; mtile += MS1) {
    const u16* xptr[4];
#pragma unroll
    for (int i = 0; i < 4; ++i) {
      int idx = mtile * 128 + rowi[i];
      int tok = (idx < cnt) ? lists[e * CAP + idx] : 0;
      xptr[i] = xb + (size_t)tok * DD + kqi[i] * 8;
    }
    floatx4 acc[4][4];
#pragma unroll
    for (int a = 0; a < 4; ++a)
#pragma unroll
      for (int b = 0; b < 4; ++b) acc[a][b] = (floatx4){0.f, 0.f, 0.f, 0.f};

    for (int kc = 0; kc < DD / 64; ++kc) {      // K = 512, BK = 64
      __syncthreads();
#pragma unroll
      for (int i = 0; i < 4; ++i) {
        int off = (tid + i * 256) * 16;
        gl2lds16(wptr[i] + kc * 64, ldsA + off);
        gl2lds16(xptr[i] + kc * 64, ldsB + off);
      }
      __syncthreads();
#pragma unroll
      for (int ks = 0; ks < 2; ++ks) {
        short8 af[4], bf[4];
#pragma unroll
        for (int t4 = 0; t4 < 4; ++t4) {
          int rA = hh * 64 + t4 * 16 + col16;
          af[t4] = *(const short8*)(ldsA + (rA * 8 + ((ks * 4 + quad) ^ (rA & 7))) * 16);
          int rB = mh * 64 + t4 * 16 + col16;
          bf[t4] = *(const short8*)(ldsB + (rB * 8 + ((ks * 4 + quad) ^ (rB & 7))) * 16);
        }
#pragma unroll
        for (int ht = 0; ht < 4; ++ht)
#pragma unroll
          for (int mt = 0; mt < 4; ++mt)
            acc[ht][mt] = __builtin_amdgcn_mfma_f32_16x16x32_bf16(af[ht], bf[mt], acc[ht][mt], 0, 0, 0);
      }
    }
    // epilogue: +b1, relu, bf16 pack (4 consecutive h per lane -> b64 store)
#pragma unroll
    for (int ht = 0; ht < 4; ++ht) {
      int hloc = nt * 128 + hh * 64 + ht * 16 + quad * 4;
      float b1v[4];
#pragma unroll
      for (int r = 0; r < 4; ++r) b1v[r] = b1[e * HH + hloc + r];
#pragma unroll
      for (int mt = 0; mt < 4; ++mt) {
        int gm = mtile * 128 + mh * 64 + mt * 16 + col16;
        if (gm < cnt) {
          u64 pk = 0;
#pragma unroll
          for (int r = 0; r < 4; ++r) {
            float f = fmaxf(acc[ht][mt][r] + b1v[r], 0.f);
            pk |= (u64)f2bf(f) << (16 * r);
          }
          *(u64*)(H + (size_t)(eOff + gm) * HH + hloc) = pk;
        }
      }
    }
  }
}

// ============ PASS 2: out[tok] (=|+=) gate * (H @ W2 + b2), full K = 2048 ============
// rmw=0 (rank A / top-1): plain store, covers every token exactly once (no memset).
// rmw=1 (rank B / top-2): plain read-add-write; race-free (one slot per token).
__global__ __launch_bounds__(256, 2)
void pass2_gemm(const u16* __restrict__ H, const u16* __restrict__ w2t,
                const float* __restrict__ b2, const int* __restrict__ counts,
                const int* __restrict__ lists, const float* __restrict__ gates,
                float* __restrict__ out, int rmw) {
  __shared__ __align__(16) char lds[32768];
  char* ldsA = lds;           // H tile   [128 m][64 k]
  char* ldsB = lds + 16384;   // W2^T tile[128 d][64 k]
  const int e = blockIdx.x & 7;
  const int nt = (blockIdx.x >> 3) & 3;    // d-tile 0..3
  const int ms = blockIdx.x >> 5;          // m-seed 0..MS2-1
  int cnt = counts[e]; if (cnt > CAP) cnt = CAP;
  int eOff = 0;
#pragma unroll
  for (int j = 0; j < EE; ++j) {
    int cj = counts[j]; if (cj > CAP) cj = CAP;
    eOff += (j < e) ? cj : 0;
  }
  const int tid = threadIdx.x, lane = tid & 63, w = tid >> 6;
  const int col16 = lane & 15, quad = lane >> 4;
  const int mh = w & 1, dh = w >> 1;

  int rowi[4], kqi[4];
  const u16* wptr[4];
#pragma unroll
  for (int i = 0; i < 4; ++i) {
    int c = tid + i * 256;
    rowi[i] = c >> 3;
    kqi[i] = (c & 7) ^ (rowi[i] & 7);
    wptr[i] = w2t + (size_t)(e * DD + nt * 128 + rowi[i]) * HH + kqi[i] * 8;
  }

  for (int mtile = ms; mtile * 128 < cnt; mtile += MS2) {
    const u16* hptr[4];
#pragma unroll
    for (int i = 0; i < 4; ++i)
      hptr[i] = H + (size_t)(eOff + mtile * 128 + rowi[i]) * HH + kqi[i] * 8;  // pad rows exist

    floatx4 acc[4][4];
#pragma unroll
    for (int a = 0; a < 4; ++a)
#pragma unroll
      for (int b = 0; b < 4; ++b) acc[a][b] = (floatx4){0.f, 0.f, 0.f, 0.f};

    for (int kc = 0; kc < HH / 64; ++kc) {   // K = 2048, BK = 64
      __syncthreads();
#pragma unroll
      for (int i = 0; i < 4; ++i) {
        int off = (tid + i * 256) * 16;
        gl2lds16(hptr[i] + kc * 64, ldsA + off);
        gl2lds16(wptr[i] + kc * 64, ldsB + off);
      }
      __syncthreads();
#pragma unroll
      for (int ks = 0; ks < 2; ++ks) {
        short8 af[4], bf[4];
#pragma unroll
        for (int t4 = 0; t4 < 4; ++t4) {
          int rA = mh * 64 + t4 * 16 + col16;
          af[t4] = *(const short8*)(ldsA + (rA * 8 + ((ks * 4 + quad) ^ (rA & 7))) * 16);
          int rB = dh * 64 + t4 * 16 + col16;
          bf[t4] = *(const short8*)(ldsB + (rB * 8 + ((ks * 4 + quad) ^ (rB & 7))) * 16);
        }
#pragma unroll
        for (int mt = 0; mt < 4; ++mt)
#pragma unroll
          for (int dt = 0; dt < 4; ++dt)
            acc[mt][dt] = __builtin_amdgcn_mfma_f32_16x16x32_bf16(af[mt], bf[dt], acc[mt][dt], 0, 0, 0);
      }
    }
    // epilogue: out (=|+=) g * (acc + b2); plain stores, no atomics
    float b2v[4];
#pragma unroll
    for (int dt = 0; dt < 4; ++dt)
      b2v[dt] = b2[e * DD + nt * 128 + dh * 64 + dt * 16 + col16];
#pragma unroll
    for (int mt = 0; mt < 4; ++mt) {
#pragma unroll
      for (int r = 0; r < 4; ++r) {
        int idx = mtile * 128 + mh * 64 + mt * 16 + quad * 4 + r;
        if (idx < cnt) {
          int tok = lists[e * CAP + idx];
          float g = gates[e * CAP + idx];
          float* orow = out + (size_t)tok * DD + nt * 128 + dh * 64;
          if (rmw) {
#pragma unroll
            for (int dt = 0; dt < 4; ++dt)
              orow[dt * 16 + col16] += g * (acc[mt][dt][r] + b2v[dt]);
          } else {
#pragma unroll
            for (int dt = 0; dt < 4; ++dt)
              orow[dt * 16 + col16] = g * (acc[mt][dt][r] + b2v[dt]);
          }
        }
      }
    }
  }
}

extern "C" void kernel_launch(void* const* d_in, const int* in_sizes, int n_in,
                              void* d_out, int out_size, void* d_ws, size_t ws_size,
                              hipStream_t stream) {
  const float* x     = (const float*)d_in[0];
  const float* noise = (const float*)d_in[1];
  const float* Wg    = (const float*)d_in[2];
  const float* bg    = (const float*)d_in[3];
  const float* Wn    = (const float*)d_in[4];
  const float* bn    = (const float*)d_in[5];
  const float* W1    = (const float*)d_in[6];
  const float* b1    = (const float*)d_in[7];
  const float* W2    = (const float*)d_in[8];
  const float* b2    = (const float*)d_in[9];
  float* out = (float*)d_out;
  char* ws = (char*)d_ws;

  // ws layout (total 202,964,992 B < 204,734,464 proven-good bound)
  u16*  w1t     = (u16*)(ws + 0x0000000);   // [E][H][D] bf16, 16 MB
  u16*  w2t     = (u16*)(ws + 0x1000000);   // [E][D][H] bf16, 16 MB
  u16*  xb      = (u16*)(ws + 0x2000000);   // [T][D] bf16, 32 MB
  int*  countsA = (int*)(ws + 0x4000000);   // [E]
  int*  countsB = (int*)(ws + 0x4000020);   // [E]
  int*  listsA  = (int*)(ws + 0x4010000);   // [E][CAP] int, 256 KB
  int*  listsB  = (int*)(ws + 0x4050000);
  float* gatesA = (float*)(ws + 0x4090000);
  float* gatesB = (float*)(ws + 0x40D0000);
  u16*  Hbuf    = (u16*)(ws + 0x4110000);   // [TT+128][HH] bf16 = 134.74 MB
  (void)ws_size;

  hipMemsetAsync(countsA, 0, 64, stream);   // covers countsA + countsB
  transpose_bf16<<<dim3(HH / 32, DD / 32, EE), dim3(32, 8), 0, stream>>>(W1, w1t, DD, HH);
  transpose_bf16<<<dim3(DD / 32, HH / 32, EE), dim3(32, 8), 0, stream>>>(W2, w2t, HH, DD);
  router_topk<<<TT / 4, 256, 0, stream>>>(x, noise, Wg, bg, Wn, bn, xb,
                                          countsA, countsB, listsA, listsB, gatesA, gatesB);

  // rank A (top-1 slots): plain store fully covers out
  pass1_gemm<<<8 * 16 * MS1, 256, 0, stream>>>(xb, w1t, b1, countsA, listsA, Hbuf);
  pass2_gemm<<<8 * 4 * MS2, 256, 0, stream>>>(Hbuf, w2t, b2, countsA, listsA, gatesA, out, 0);
  // rank B (top-2 slots): race-free read-add-write
  pass1_gemm<<<8 * 16 * MS1, 256, 0, stream>>>(xb, w1t, b1, countsB, listsB, Hbuf);
  pass2_gemm<<<8 * 4 * MS2, 256, 0, stream>>>(Hbuf, w2t, b2, countsB, listsB, gatesB, out, 1);
}

// Round 3
// 767.207 us; speedup vs baseline: 1.8103x; 1.8103x over previous
//
#include <hip/hip_runtime.h>

#define TT 32768   // B*S tokens
#define DD 512
#define HH 2048
#define EE 8
#define CAP 8192   // per-expert per-rank slot capacity (mean 4096, +68 sigma headroom)

typedef unsigned short u16;
typedef unsigned int u32;
typedef unsigned long long u64;
using short8  = __attribute__((ext_vector_type(8))) short;
using floatx4 = __attribute__((ext_vector_type(4))) float;

__device__ __forceinline__ u16 f2bf(float f) {
  unsigned u = __float_as_uint(f);
  u += 0x7FFFu + ((u >> 16) & 1u);   // RNE; inputs are finite
  return (u16)(u >> 16);
}

// async global->LDS, 16B per lane; lds dest is wave-uniform base + lane*16
__device__ __forceinline__ void gl2lds16(const u16* g, char* l) {
  __builtin_amdgcn_global_load_lds(
      (const __attribute__((address_space(1))) u32*)(const void*)g,
      (__attribute__((address_space(3))) u32*)(void*)l, 16, 0, 0);
}

// ------------- transpose fp32 [E][R][C] -> bf16 [E][C][R] -------------
__global__ void transpose_bf16(const float* __restrict__ in, u16* __restrict__ out, int R, int C) {
  __shared__ float tile[32][33];
  int e = blockIdx.z;
  const float* src = in + (size_t)e * R * C;
  u16* dst = out + (size_t)e * R * C;
  int tx = threadIdx.x, ty = threadIdx.y;
  int c0 = blockIdx.x * 32, r0 = blockIdx.y * 32;
#pragma unroll
  for (int i = 0; i < 32; i += 8)
    tile[ty + i][tx] = src[(size_t)(r0 + ty + i) * C + c0 + tx];
  __syncthreads();
#pragma unroll
  for (int i = 0; i < 32; i += 8)
    dst[(size_t)(c0 + ty + i) * R + r0 + tx] = f2bf(tile[tx][ty + i]);
}

// ------- router pass 1: one wave per token; NO atomics (round-2 lesson: per-wave
// global atomics onto 16 words serialized -> 768 us). Emits topk/g + bf16 x row. -------
__global__ void router_topk(const float* __restrict__ x, const float* __restrict__ noise,
                            const float* __restrict__ Wg, const float* __restrict__ bg,
                            const float* __restrict__ Wn, const float* __restrict__ bn,
                            u16* __restrict__ xb, int* __restrict__ topk_i,
                            float* __restrict__ topk_g0, float* __restrict__ topk_g1) {
  const int t = (blockIdx.x * blockDim.x + threadIdx.x) >> 6;
  const int lane = threadIdx.x & 63;
  if (t >= TT) return;
  const float4* xr = (const float4*)(x + (size_t)t * DD) + lane * 2;
  float4 xa = xr[0], xbv = xr[1];
  float xv[8] = {xa.x, xa.y, xa.z, xa.w, xbv.x, xbv.y, xbv.z, xbv.w};
  // fused fp32->bf16 convert of x (wave already holds the whole row)
  {
    ushort4 o0, o1;
    o0.x = f2bf(xa.x); o0.y = f2bf(xa.y); o0.z = f2bf(xa.z); o0.w = f2bf(xa.w);
    o1.x = f2bf(xbv.x); o1.y = f2bf(xbv.y); o1.z = f2bf(xbv.z); o1.w = f2bf(xbv.w);
    ushort4* xo = (ushort4*)(xb + (size_t)t * DD) + lane * 2;
    xo[0] = o0; xo[1] = o1;
  }
  float pg[8], pn[8];
#pragma unroll
  for (int e = 0; e < 8; ++e) { pg[e] = 0.f; pn[e] = 0.f; }
  const float4* wg4 = (const float4*)(Wg + lane * 64);
  const float4* wn4 = (const float4*)(Wn + lane * 64);
#pragma unroll
  for (int j = 0; j < 8; ++j) {
    float xj = xv[j];
    float4 a = wg4[2 * j], b = wg4[2 * j + 1];
    pg[0] += xj * a.x; pg[1] += xj * a.y; pg[2] += xj * a.z; pg[3] += xj * a.w;
    pg[4] += xj * b.x; pg[5] += xj * b.y; pg[6] += xj * b.z; pg[7] += xj * b.w;
    a = wn4[2 * j]; b = wn4[2 * j + 1];
    pn[0] += xj * a.x; pn[1] += xj * a.y; pn[2] += xj * a.z; pn[3] += xj * a.w;
    pn[4] += xj * b.x; pn[5] += xj * b.y; pn[6] += xj * b.z; pn[7] += xj * b.w;
  }
#pragma unroll
  for (int off = 32; off; off >>= 1) {
#pragma unroll
    for (int e = 0; e < 8; ++e) {
      pg[e] += __shfl_xor(pg[e], off);
      pn[e] += __shfl_xor(pn[e], off);
    }
  }
  if (lane == 0) {
    float noisy[8];
#pragma unroll
    for (int e = 0; e < 8; ++e) {
      float nl = pn[e] + bn[e];
      float sp = (nl > 20.f) ? nl : log1pf(expf(nl));
      noisy[e] = pg[e] + bg[e] + noise[(size_t)t * EE + e] * sp;
    }
    int i0 = 0; float v0 = noisy[0];
#pragma unroll
    for (int e = 1; e < 8; ++e) if (noisy[e] > v0) { v0 = noisy[e]; i0 = e; }
    int i1 = -1; float v1 = -3.4e38f;
#pragma unroll
    for (int e = 0; e < 8; ++e) if (e != i0 && noisy[e] > v1) { v1 = noisy[e]; i1 = e; }
    float ed = expf(v1 - v0);
    float inv = 1.f / (1.f + ed);
    topk_i[t] = i0 | (i1 << 8);
    topk_g0[t] = inv;
    topk_g1[t] = ed * inv;
  }
}

// ---- router pass 2: LDS double-histogram; 16 aggregated global atomics per 256 tokens.
// rank A = top-1 slot, rank B = top-2 slot (exactly one slot per token per rank). ----
__global__ void router_bin(const int* __restrict__ topk_i, const float* __restrict__ tg0,
                           const float* __restrict__ tg1,
                           int* __restrict__ countsA, int* __restrict__ countsB,
                           int* __restrict__ listsA, int* __restrict__ listsB,
                           float* __restrict__ gatesA, float* __restrict__ gatesB) {
  __shared__ int histA[EE], histB[EE], baseA[EE], baseB[EE];
  int t = blockIdx.x * 256 + threadIdx.x;
  if (threadIdx.x < EE) { histA[threadIdx.x] = 0; histB[threadIdx.x] = 0; }
  __syncthreads();
  int p = topk_i[t];
  int i0 = p & 255, i1 = p >> 8;
  int r0 = atomicAdd(&histA[i0], 1);
  int r1 = atomicAdd(&histB[i1], 1);
  __syncthreads();
  if (threadIdx.x < EE) {
    baseA[threadIdx.x] = atomicAdd(&countsA[threadIdx.x], histA[threadIdx.x]);
    baseB[threadIdx.x] = atomicAdd(&countsB[threadIdx.x], histB[threadIdx.x]);
  }
  __syncthreads();
  int s0 = baseA[i0] + r0, s1 = baseB[i1] + r1;
  if (s0 < CAP) { listsA[i0 * CAP + s0] = t; gatesA[i0 * CAP + s0] = tg0[t]; }
  if (s1 < CAP) { listsB[i1 * CAP + s1] = t; gatesB[i1 * CAP + s1] = tg1[t]; }
}

// ============ PASS 1: H = relu(X_gathered @ W1 + b1)  (bf16, full 2048-wide) ============
// 128x128 tile, BK=64, 4 waves x (64x64), XOR-swizzled 16B LDS chunks.
// blockIdx.x = e + 8*(nt + 16*ms): expert in low bits pins the expert to one XCD
// (grid.x % 8 == 0); all 16 ntile-blocks of an (e, ms) pair are co-resident on that
// XCD so they share the same X m-tile through L2 (fetch X once, reuse 16x).
#define MS1 6
#define MS2 16
__global__ __launch_bounds__(256, 2)
void pass1_gemm(const u16* __restrict__ xb, const u16* __restrict__ w1t,
                const float* __restrict__ b1, const int* __restrict__ counts,
                const int* __restrict__ lists, u16* __restrict__ H) {
  __shared__ __align__(16) char lds[32768];
  char* ldsA = lds;           // W1^T tile [128 h][64 k]
  char* ldsB = lds + 16384;   // X tile    [128 m][64 k]
  const int e = blockIdx.x & 7;
  const int nt = (blockIdx.x >> 3) & 15;   // h-tile 0..15
  const int ms = blockIdx.x >> 7;          // m-seed 0..MS1-1
  int cnt = counts[e]; if (cnt > CAP) cnt = CAP;
  int eOff = 0;
#pragma unroll
  for (int j = 0; j < EE; ++j) {
    int cj = counts[j]; if (cj > CAP) cj = CAP;
    eOff += (j < e) ? cj : 0;
  }
  const int tid = threadIdx.x, lane = tid & 63, w = tid >> 6;
  const int col16 = lane & 15, quad = lane >> 4;
  const int hh = w & 1, mh = w >> 1;

  int rowi[4], kqi[4];
  const u16* wptr[4];
#pragma unroll
  for (int i = 0; i < 4; ++i) {
    int c = tid + i * 256;
    rowi[i] = c >> 3;
    kqi[i] = (c & 7) ^ (rowi[i] & 7);
    wptr[i] = w1t + (size_t)(e * HH + nt * 128 + rowi[i]) * DD + kqi[i] * 8;
  }

  for (int mtile = ms; mtile * 128 < cnt; mtile += MS1) {
    const u16* xptr[4];
#pragma unroll
    for (int i = 0; i < 4; ++i) {
      int idx = mtile * 128 + rowi[i];
      int tok = (idx < cnt) ? lists[e * CAP + idx] : 0;
      xptr[i] = xb + (size_t)tok * DD + kqi[i] * 8;
    }
    floatx4 acc[4][4];
#pragma unroll
    for (int a = 0; a < 4; ++a)
#pragma unroll
      for (int b = 0; b < 4; ++b) acc[a][b] = (floatx4){0.f, 0.f, 0.f, 0.f};

    for (int kc = 0; kc < DD / 64; ++kc) {      // K = 512, BK = 64
      __syncthreads();
#pragma unroll
      for (int i = 0; i < 4; ++i) {
        int off = (tid + i * 256) * 16;
        gl2lds16(wptr[i] + kc * 64, ldsA + off);
        gl2lds16(xptr[i] + kc * 64, ldsB + off);
      }
      __syncthreads();
#pragma unroll
      for (int ks = 0; ks < 2; ++ks) {
        short8 af[4], bf[4];
#pragma unroll
        for (int t4 = 0; t4 < 4; ++t4) {
          int rA = hh * 64 + t4 * 16 + col16;
          af[t4] = *(const short8*)(ldsA + (rA * 8 + ((ks * 4 + quad) ^ (rA & 7))) * 16);
          int rB = mh * 64 + t4 * 16 + col16;
          bf[t4] = *(const short8*)(ldsB + (rB * 8 + ((ks * 4 + quad) ^ (rB & 7))) * 16);
        }
#pragma unroll
        for (int ht = 0; ht < 4; ++ht)
#pragma unroll
          for (int mt = 0; mt < 4; ++mt)
            acc[ht][mt] = __builtin_amdgcn_mfma_f32_16x16x32_bf16(af[ht], bf[mt], acc[ht][mt], 0, 0, 0);
      }
    }
    // epilogue: +b1, relu, bf16 pack (4 consecutive h per lane -> b64 store)
#pragma unroll
    for (int ht = 0; ht < 4; ++ht) {
      int hloc = nt * 128 + hh * 64 + ht * 16 + quad * 4;
      float b1v[4];
#pragma unroll
      for (int r = 0; r < 4; ++r) b1v[r] = b1[e * HH + hloc + r];
#pragma unroll
      for (int mt = 0; mt < 4; ++mt) {
        int gm = mtile * 128 + mh * 64 + mt * 16 + col16;
        if (gm < cnt) {
          u64 pk = 0;
#pragma unroll
          for (int r = 0; r < 4; ++r) {
            float f = fmaxf(acc[ht][mt][r] + b1v[r], 0.f);
            pk |= (u64)f2bf(f) << (16 * r);
          }
          *(u64*)(H + (size_t)(eOff + gm) * HH + hloc) = pk;
        }
      }
    }
  }
}

// ============ PASS 2: out[tok] (=|+=) gate * (H @ W2 + b2), full K = 2048 ============
// rmw=0 (rank A / top-1): plain store, covers every token exactly once (no memset).
// rmw=1 (rank B / top-2): plain read-add-write; race-free (one slot per token).
__global__ __launch_bounds__(256, 2)
void pass2_gemm(const u16* __restrict__ H, const u16* __restrict__ w2t,
                const float* __restrict__ b2, const int* __restrict__ counts,
                const int* __restrict__ lists, const float* __restrict__ gates,
                float* __restrict__ out, int rmw) {
  __shared__ __align__(16) char lds[32768];
  char* ldsA = lds;           // H tile   [128 m][64 k]
  char* ldsB = lds + 16384;   // W2^T tile[128 d][64 k]
  const int e = blockIdx.x & 7;
  const int nt = (blockIdx.x >> 3) & 3;    // d-tile 0..3
  const int ms = blockIdx.x >> 5;          // m-seed 0..MS2-1
  int cnt = counts[e]; if (cnt > CAP) cnt = CAP;
  int eOff = 0;
#pragma unroll
  for (int j = 0; j < EE; ++j) {
    int cj = counts[j]; if (cj > CAP) cj = CAP;
    eOff += (j < e) ? cj : 0;
  }
  const int tid = threadIdx.x, lane = tid & 63, w = tid >> 6;
  const int col16 = lane & 15, quad = lane >> 4;
  const int mh = w & 1, dh = w >> 1;

  int rowi[4], kqi[4];
  const u16* wptr[4];
#pragma unroll
  for (int i = 0; i < 4; ++i) {
    int c = tid + i * 256;
    rowi[i] = c >> 3;
    kqi[i] = (c & 7) ^ (rowi[i] & 7);
    wptr[i] = w2t + (size_t)(e * DD + nt * 128 + rowi[i]) * HH + kqi[i] * 8;
  }

  for (int mtile = ms; mtile * 128 < cnt; mtile += MS2) {
    const u16* hptr[4];
#pragma unroll
    for (int i = 0; i < 4; ++i)
      hptr[i] = H + (size_t)(eOff + mtile * 128 + rowi[i]) * HH + kqi[i] * 8;  // pad rows exist

    floatx4 acc[4][4];
#pragma unroll
    for (int a = 0; a < 4; ++a)
#pragma unroll
      for (int b = 0; b < 4; ++b) acc[a][b] = (floatx4){0.f, 0.f, 0.f, 0.f};

    for (int kc = 0; kc < HH / 64; ++kc) {   // K = 2048, BK = 64
      __syncthreads();
#pragma unroll
      for (int i = 0; i < 4; ++i) {
        int off = (tid + i * 256) * 16;
        gl2lds16(hptr[i] + kc * 64, ldsA + off);
        gl2lds16(wptr[i] + kc * 64, ldsB + off);
      }
      __syncthreads();
#pragma unroll
      for (int ks = 0; ks < 2; ++ks) {
        short8 af[4], bf[4];
#pragma unroll
        for (int t4 = 0; t4 < 4; ++t4) {
          int rA = mh * 64 + t4 * 16 + col16;
          af[t4] = *(const short8*)(ldsA + (rA * 8 + ((ks * 4 + quad) ^ (rA & 7))) * 16);
          int rB = dh * 64 + t4 * 16 + col16;
          bf[t4] = *(const short8*)(ldsB + (rB * 8 + ((ks * 4 + quad) ^ (rB & 7))) * 16);
        }
#pragma unroll
        for (int mt = 0; mt < 4; ++mt)
#pragma unroll
          for (int dt = 0; dt < 4; ++dt)
            acc[mt][dt] = __builtin_amdgcn_mfma_f32_16x16x32_bf16(af[mt], bf[dt], acc[mt][dt], 0, 0, 0);
      }
    }
    // epilogue: out (=|+=) g * (acc + b2); plain stores, no atomics
    float b2v[4];
#pragma unroll
    for (int dt = 0; dt < 4; ++dt)
      b2v[dt] = b2[e * DD + nt * 128 + dh * 64 + dt * 16 + col16];
#pragma unroll
    for (int mt = 0; mt < 4; ++mt) {
#pragma unroll
      for (int r = 0; r < 4; ++r) {
        int idx = mtile * 128 + mh * 64 + mt * 16 + quad * 4 + r;
        if (idx < cnt) {
          int tok = lists[e * CAP + idx];
          float g = gates[e * CAP + idx];
          float* orow = out + (size_t)tok * DD + nt * 128 + dh * 64;
          if (rmw) {
#pragma unroll
            for (int dt = 0; dt < 4; ++dt)
              orow[dt * 16 + col16] += g * (acc[mt][dt][r] + b2v[dt]);
          } else {
#pragma unroll
            for (int dt = 0; dt < 4; ++dt)
              orow[dt * 16 + col16] = g * (acc[mt][dt][r] + b2v[dt]);
          }
        }
      }
    }
  }
}

extern "C" void kernel_launch(void* const* d_in, const int* in_sizes, int n_in,
                              void* d_out, int out_size, void* d_ws, size_t ws_size,
                              hipStream_t stream) {
  const float* x     = (const float*)d_in[0];
  const float* noise = (const float*)d_in[1];
  const float* Wg    = (const float*)d_in[2];
  const float* bg    = (const float*)d_in[3];
  const float* Wn    = (const float*)d_in[4];
  const float* bn    = (const float*)d_in[5];
  const float* W1    = (const float*)d_in[6];
  const float* b1    = (const float*)d_in[7];
  const float* W2    = (const float*)d_in[8];
  const float* b2    = (const float*)d_in[9];
  float* out = (float*)d_out;
  char* ws = (char*)d_ws;

  // ws layout (ends at 203,292,672 B < 204,734,464 proven-good bound)
  u16*  w1t     = (u16*)(ws + 0x0000000);   // [E][H][D] bf16, 16 MB
  u16*  w2t     = (u16*)(ws + 0x1000000);   // [E][D][H] bf16, 16 MB
  u16*  xb      = (u16*)(ws + 0x2000000);   // [T][D] bf16, 32 MB
  int*  countsA = (int*)(ws + 0x4000000);   // [E]
  int*  countsB = (int*)(ws + 0x4000020);   // [E]
  int*  listsA  = (int*)(ws + 0x4010000);   // [E][CAP] int, 256 KB
  int*  listsB  = (int*)(ws + 0x4050000);
  float* gatesA = (float*)(ws + 0x4090000);
  float* gatesB = (float*)(ws + 0x40D0000);
  int*  topk_i  = (int*)(ws + 0x4110000);   // [T] int, 128 KB
  float* tg0    = (float*)(ws + 0x4130000); // [T]
  float* tg1    = (float*)(ws + 0x4150000); // [T]
  u16*  Hbuf    = (u16*)(ws + 0x4170000);   // [TT+128][HH] bf16 = 134.74 MB
  (void)ws_size;

  hipMemsetAsync(countsA, 0, 64, stream);   // covers countsA + countsB
  transpose_bf16<<<dim3(HH / 32, DD / 32, EE), dim3(32, 8), 0, stream>>>(W1, w1t, DD, HH);
  transpose_bf16<<<dim3(DD / 32, HH / 32, EE), dim3(32, 8), 0, stream>>>(W2, w2t, HH, DD);
  router_topk<<<TT / 4, 256, 0, stream>>>(x, noise, Wg, bg, Wn, bn, xb, topk_i, tg0, tg1);
  router_bin<<<TT / 256, 256, 0, stream>>>(topk_i, tg0, tg1, countsA, countsB,
                                           listsA, listsB, gatesA, gatesB);

  // rank A (top-1 slots): plain store fully covers out
  pass1_gemm<<<8 * 16 * MS1, 256, 0, stream>>>(xb, w1t, b1, countsA, listsA, Hbuf);
  pass2_gemm<<<8 * 4 * MS2, 256, 0, stream>>>(Hbuf, w2t, b2, countsA, listsA, gatesA, out, 0);
  // rank B (top-2 slots): race-free read-add-write
  pass1_gemm<<<8 * 16 * MS1, 256, 0, stream>>>(xb, w1t, b1, countsB, listsB, Hbuf);
  pass2_gemm<<<8 * 4 * MS2, 256, 0, stream>>>(Hbuf, w2t, b2, countsB, listsB, gatesB, out, 1);
}

// Round 4
// 761.880 us; speedup vs baseline: 1.8230x; 1.0070x over previous
//
#include <hip/hip_runtime.h>

#define TT 32768   // B*S tokens
#define DD 512
#define HH 2048
#define EE 8
#define CAP 8192   // per-expert per-rank slot capacity (mean 4096, +68 sigma headroom)

typedef unsigned short u16;
typedef unsigned int u32;
typedef unsigned long long u64;
using short8  = __attribute__((ext_vector_type(8))) short;
using floatx4 = __attribute__((ext_vector_type(4))) float;

__device__ __forceinline__ u16 f2bf(float f) {
  unsigned u = __float_as_uint(f);
  u += 0x7FFFu + ((u >> 16) & 1u);   // RNE; inputs are finite
  return (u16)(u >> 16);
}

// async global->LDS, 16B per lane; lds dest is wave-uniform base + lane*16
__device__ __forceinline__ void gl2lds16(const u16* g, char* l) {
  __builtin_amdgcn_global_load_lds(
      (const __attribute__((address_space(1))) u32*)(const void*)g,
      (__attribute__((address_space(3))) u32*)(void*)l, 16, 0, 0);
}

// ------------- transpose fp32 [E][R][C] -> bf16 [E][C][R] -------------
__global__ void transpose_bf16(const float* __restrict__ in, u16* __restrict__ out, int R, int C) {
  __shared__ float tile[32][33];
  int e = blockIdx.z;
  const float* src = in + (size_t)e * R * C;
  u16* dst = out + (size_t)e * R * C;
  int tx = threadIdx.x, ty = threadIdx.y;
  int c0 = blockIdx.x * 32, r0 = blockIdx.y * 32;
#pragma unroll
  for (int i = 0; i < 32; i += 8)
    tile[ty + i][tx] = src[(size_t)(r0 + ty + i) * C + c0 + tx];
  __syncthreads();
#pragma unroll
  for (int i = 0; i < 32; i += 8)
    dst[(size_t)(c0 + ty + i) * R + r0 + tx] = f2bf(tile[tx][ty + i]);
}

// ---- router weight prep: wrt[16][512] f32; rows 0-7 = Wg^T, rows 8-15 = Wn^T ----
__global__ void prep_router_w(const float* __restrict__ Wg, const float* __restrict__ Wn,
                              float* __restrict__ wrt) {
  int c = blockIdx.x;          // 0..15
  int k = threadIdx.x;         // 0..511
  wrt[c * 512 + k] = (c < 8) ? Wg[k * 8 + c] : Wn[k * 8 + (c - 8)];
}

// ------- router pass 1 (rewritten): block = 16 tokens; thread (tok, col) owns one
// of the 16 router dot products (8 Wg cols + 8 Wn cols). x staged once in LDS
// (row pad +4 floats -> the 4 tokens of a wave hit 4 distinct banks), weights
// from the 32 KB L1-hot wrt table. No 64-lane butterfly: top-2 is a 3-step
// shuffle over 8 lanes. Round-3 lesson: 1 wave/token re-read 32 KB weights and
// did 192 shfl-ops per token -> 155 us. -------
__global__ __launch_bounds__(256)
void router_topk(const float* __restrict__ x, const float* __restrict__ noise,
                 const float* __restrict__ wrt, const float* __restrict__ bg,
                 const float* __restrict__ bn,
                 u16* __restrict__ xb, int* __restrict__ topk_i,
                 float* __restrict__ tg0, float* __restrict__ tg1) {
  __shared__ __align__(16) float xs[16 * 516];   // 16 rows, stride 516 floats
  const int tid = threadIdx.x;
  const int blk = blockIdx.x;                    // 16 tokens per block
  // stage x (16 rows) + fused bf16 emit (coalesced float4 / ushort4)
  const float4* xg = (const float4*)(x + (size_t)blk * 16 * DD);
  ushort4* xo = (ushort4*)(xb + (size_t)blk * 16 * DD);
#pragma unroll
  for (int j = 0; j < 8; ++j) {
    int L = tid + j * 256;                 // 0..2047 linear float4 index
    int tk = L >> 7, j4 = L & 127;
    float4 v = xg[L];
    *(float4*)(xs + tk * 516 + j4 * 4) = v;
    ushort4 o; o.x = f2bf(v.x); o.y = f2bf(v.y); o.z = f2bf(v.z); o.w = f2bf(v.w);
    xo[L] = o;
  }
  __syncthreads();
  const int tok = tid >> 4;        // 0..15
  const int col = tid & 15;        // 0..15: 0-7 Wg cols, 8-15 Wn cols
  const float4* wr = (const float4*)(wrt + col * 512);
  const float4* xr = (const float4*)(xs + tok * 516);
  float acc = 0.f;
#pragma unroll 4
  for (int k = 0; k < 128; ++k) {
    float4 xv = xr[k];
    float4 wv = wr[k];
    acc += xv.x * wv.x + xv.y * wv.y + xv.z * wv.z + xv.w * wv.w;
  }
  const int t = blk * 16 + tok;
  float other = __shfl_xor(acc, 8);   // lanes col<8: acc=pg[col], other=pn[col]
  float noisy = -3.4e38f;
  if (col < 8) {
    float nl = other + bn[col];
    float sp = (nl > 20.f) ? nl : log1pf(expf(nl));
    noisy = acc + bg[col] + noise[(size_t)t * EE + col] * sp;
  }
  // top-1 over the 8 valid lanes (xor 1,2,4 stays inside each group of 8)
  float v = noisy; int vi = col;
#pragma unroll
  for (int off = 1; off <= 4; off <<= 1) {
    float ov = __shfl_xor(v, off);
    int   oi = __shfl_xor(vi, off);
    if (ov > v || (ov == v && oi < vi)) { v = ov; vi = oi; }
  }
  // top-2: mask out winner, reduce again
  float v2 = (col == vi) ? -3.4e38f : noisy;
  int vi2 = col;
#pragma unroll
  for (int off = 1; off <= 4; off <<= 1) {
    float ov = __shfl_xor(v2, off);
    int   oi = __shfl_xor(vi2, off);
    if (ov > v2 || (ov == v2 && oi < vi2)) { v2 = ov; vi2 = oi; }
  }
  if (col == 0) {
    float ed = expf(v2 - v);
    float inv = 1.f / (1.f + ed);
    topk_i[t] = vi | (vi2 << 8);
    tg0[t] = inv;
    tg1[t] = ed * inv;
  }
}

// ---- router pass 2: LDS double-histogram; 16 aggregated global atomics per 256 tokens.
// rank A = top-1 slot, rank B = top-2 slot (exactly one slot per token per rank). ----
__global__ void router_bin(const int* __restrict__ topk_i, const float* __restrict__ tg0,
                           const float* __restrict__ tg1,
                           int* __restrict__ countsA, int* __restrict__ countsB,
                           int* __restrict__ listsA, int* __restrict__ listsB,
                           float* __restrict__ gatesA, float* __restrict__ gatesB) {
  __shared__ int histA[EE], histB[EE], baseA[EE], baseB[EE];
  int t = blockIdx.x * 256 + threadIdx.x;
  if (threadIdx.x < EE) { histA[threadIdx.x] = 0; histB[threadIdx.x] = 0; }
  __syncthreads();
  int p = topk_i[t];
  int i0 = p & 255, i1 = p >> 8;
  int r0 = atomicAdd(&histA[i0], 1);
  int r1 = atomicAdd(&histB[i1], 1);
  __syncthreads();
  if (threadIdx.x < EE) {
    baseA[threadIdx.x] = atomicAdd(&countsA[threadIdx.x], histA[threadIdx.x]);
    baseB[threadIdx.x] = atomicAdd(&countsB[threadIdx.x], histB[threadIdx.x]);
  }
  __syncthreads();
  int s0 = baseA[i0] + r0, s1 = baseB[i1] + r1;
  if (s0 < CAP) { listsA[i0 * CAP + s0] = t; gatesA[i0 * CAP + s0] = tg0[t]; }
  if (s1 < CAP) { listsB[i1 * CAP + s1] = t; gatesB[i1 * CAP + s1] = tg1[t]; }
}

// ============ PASS 1: H = relu(X_gathered @ W1 + b1)  (bf16, full 2048-wide) ============
// 128x128 tile, BK=64, 4 waves x (64x64), XOR-swizzled 16B LDS chunks.
// blockIdx.x = e + 8*(nt + 16*ms); grid 1024 blocks = 4 blocks/CU (LDS 32KB allows 5;
// keep __launch_bounds__(256,2) -- the (256,4) VGPR squeeze was round-1's regression).
#define MS1 8
#define MS2 32
__global__ __launch_bounds__(256, 2)
void pass1_gemm(const u16* __restrict__ xb, const u16* __restrict__ w1t,
                const float* __restrict__ b1, const int* __restrict__ counts,
                const int* __restrict__ lists, u16* __restrict__ H) {
  __shared__ __align__(16) char lds[32768];
  char* ldsA = lds;           // W1^T tile [128 h][64 k]
  char* ldsB = lds + 16384;   // X tile    [128 m][64 k]
  const int e = blockIdx.x & 7;
  const int nt = (blockIdx.x >> 3) & 15;   // h-tile 0..15
  const int ms = blockIdx.x >> 7;          // m-seed 0..MS1-1
  int cnt = counts[e]; if (cnt > CAP) cnt = CAP;
  int eOff = 0;
#pragma unroll
  for (int j = 0; j < EE; ++j) {
    int cj = counts[j]; if (cj > CAP) cj = CAP;
    eOff += (j < e) ? cj : 0;
  }
  const int tid = threadIdx.x, lane = tid & 63, w = tid >> 6;
  const int col16 = lane & 15, quad = lane >> 4;
  const int hh = w & 1, mh = w >> 1;

  int rowi[4], kqi[4];
  const u16* wptr[4];
#pragma unroll
  for (int i = 0; i < 4; ++i) {
    int c = tid + i * 256;
    rowi[i] = c >> 3;
    kqi[i] = (c & 7) ^ (rowi[i] & 7);
    wptr[i] = w1t + (size_t)(e * HH + nt * 128 + rowi[i]) * DD + kqi[i] * 8;
  }

  for (int mtile = ms; mtile * 128 < cnt; mtile += MS1) {
    const u16* xptr[4];
#pragma unroll
    for (int i = 0; i < 4; ++i) {
      int idx = mtile * 128 + rowi[i];
      int tok = (idx < cnt) ? lists[e * CAP + idx] : 0;
      xptr[i] = xb + (size_t)tok * DD + kqi[i] * 8;
    }
    floatx4 acc[4][4];
#pragma unroll
    for (int a = 0; a < 4; ++a)
#pragma unroll
      for (int b = 0; b < 4; ++b) acc[a][b] = (floatx4){0.f, 0.f, 0.f, 0.f};

    for (int kc = 0; kc < DD / 64; ++kc) {      // K = 512, BK = 64
      __syncthreads();
#pragma unroll
      for (int i = 0; i < 4; ++i) {
        int off = (tid + i * 256) * 16;
        gl2lds16(wptr[i] + kc * 64, ldsA + off);
        gl2lds16(xptr[i] + kc * 64, ldsB + off);
      }
      __syncthreads();
#pragma unroll
      for (int ks = 0; ks < 2; ++ks) {
        short8 af[4], bf[4];
#pragma unroll
        for (int t4 = 0; t4 < 4; ++t4) {
          int rA = hh * 64 + t4 * 16 + col16;
          af[t4] = *(const short8*)(ldsA + (rA * 8 + ((ks * 4 + quad) ^ (rA & 7))) * 16);
          int rB = mh * 64 + t4 * 16 + col16;
          bf[t4] = *(const short8*)(ldsB + (rB * 8 + ((ks * 4 + quad) ^ (rB & 7))) * 16);
        }
#pragma unroll
        for (int ht = 0; ht < 4; ++ht)
#pragma unroll
          for (int mt = 0; mt < 4; ++mt)
            acc[ht][mt] = __builtin_amdgcn_mfma_f32_16x16x32_bf16(af[ht], bf[mt], acc[ht][mt], 0, 0, 0);
      }
    }
    // epilogue: +b1, relu, bf16 pack (4 consecutive h per lane -> b64 store)
#pragma unroll
    for (int ht = 0; ht < 4; ++ht) {
      int hloc = nt * 128 + hh * 64 + ht * 16 + quad * 4;
      float b1v[4];
#pragma unroll
      for (int r = 0; r < 4; ++r) b1v[r] = b1[e * HH + hloc + r];
#pragma unroll
      for (int mt = 0; mt < 4; ++mt) {
        int gm = mtile * 128 + mh * 64 + mt * 16 + col16;
        if (gm < cnt) {
          u64 pk = 0;
#pragma unroll
          for (int r = 0; r < 4; ++r) {
            float f = fmaxf(acc[ht][mt][r] + b1v[r], 0.f);
            pk |= (u64)f2bf(f) << (16 * r);
          }
          *(u64*)(H + (size_t)(eOff + gm) * HH + hloc) = pk;
        }
      }
    }
  }
}

// ============ PASS 2: out[tok] (=|+=) gate * (H @ W2 + b2), full K = 2048 ============
// rmw=0 (rank A / top-1): plain store, covers every token exactly once (no memset).
// rmw=1 (rank B / top-2): plain read-add-write; race-free (one slot per token).
__global__ __launch_bounds__(256, 2)
void pass2_gemm(const u16* __restrict__ H, const u16* __restrict__ w2t,
                const float* __restrict__ b2, const int* __restrict__ counts,
                const int* __restrict__ lists, const float* __restrict__ gates,
                float* __restrict__ out, int rmw) {
  __shared__ __align__(16) char lds[32768];
  char* ldsA = lds;           // H tile   [128 m][64 k]
  char* ldsB = lds + 16384;   // W2^T tile[128 d][64 k]
  const int e = blockIdx.x & 7;
  const int nt = (blockIdx.x >> 3) & 3;    // d-tile 0..3
  const int ms = blockIdx.x >> 5;          // m-seed 0..MS2-1
  int cnt = counts[e]; if (cnt > CAP) cnt = CAP;
  int eOff = 0;
#pragma unroll
  for (int j = 0; j < EE; ++j) {
    int cj = counts[j]; if (cj > CAP) cj = CAP;
    eOff += (j < e) ? cj : 0;
  }
  const int tid = threadIdx.x, lane = tid & 63, w = tid >> 6;
  const int col16 = lane & 15, quad = lane >> 4;
  const int mh = w & 1, dh = w >> 1;

  int rowi[4], kqi[4];
  const u16* wptr[4];
#pragma unroll
  for (int i = 0; i < 4; ++i) {
    int c = tid + i * 256;
    rowi[i] = c >> 3;
    kqi[i] = (c & 7) ^ (rowi[i] & 7);
    wptr[i] = w2t + (size_t)(e * DD + nt * 128 + rowi[i]) * HH + kqi[i] * 8;
  }

  for (int mtile = ms; mtile * 128 < cnt; mtile += MS2) {
    const u16* hptr[4];
#pragma unroll
    for (int i = 0; i < 4; ++i)
      hptr[i] = H + (size_t)(eOff + mtile * 128 + rowi[i]) * HH + kqi[i] * 8;  // pad rows exist

    floatx4 acc[4][4];
#pragma unroll
    for (int a = 0; a < 4; ++a)
#pragma unroll
      for (int b = 0; b < 4; ++b) acc[a][b] = (floatx4){0.f, 0.f, 0.f, 0.f};

    for (int kc = 0; kc < HH / 64; ++kc) {   // K = 2048, BK = 64
      __syncthreads();
#pragma unroll
      for (int i = 0; i < 4; ++i) {
        int off = (tid + i * 256) * 16;
        gl2lds16(hptr[i] + kc * 64, ldsA + off);
        gl2lds16(wptr[i] + kc * 64, ldsB + off);
      }
      __syncthreads();
#pragma unroll
      for (int ks = 0; ks < 2; ++ks) {
        short8 af[4], bf[4];
#pragma unroll
        for (int t4 = 0; t4 < 4; ++t4) {
          int rA = mh * 64 + t4 * 16 + col16;
          af[t4] = *(const short8*)(ldsA + (rA * 8 + ((ks * 4 + quad) ^ (rA & 7))) * 16);
          int rB = dh * 64 + t4 * 16 + col16;
          bf[t4] = *(const short8*)(ldsB + (rB * 8 + ((ks * 4 + quad) ^ (rB & 7))) * 16);
        }
#pragma unroll
        for (int mt = 0; mt < 4; ++mt)
#pragma unroll
          for (int dt = 0; dt < 4; ++dt)
            acc[mt][dt] = __builtin_amdgcn_mfma_f32_16x16x32_bf16(af[mt], bf[dt], acc[mt][dt], 0, 0, 0);
      }
    }
    // epilogue: out (=|+=) g * (acc + b2); plain stores, no atomics
    float b2v[4];
#pragma unroll
    for (int dt = 0; dt < 4; ++dt)
      b2v[dt] = b2[e * DD + nt * 128 + dh * 64 + dt * 16 + col16];
#pragma unroll
    for (int mt = 0; mt < 4; ++mt) {
#pragma unroll
      for (int r = 0; r < 4; ++r) {
        int idx = mtile * 128 + mh * 64 + mt * 16 + quad * 4 + r;
        if (idx < cnt) {
          int tok = lists[e * CAP + idx];
          float g = gates[e * CAP + idx];
          float* orow = out + (size_t)tok * DD + nt * 128 + dh * 64;
          if (rmw) {
#pragma unroll
            for (int dt = 0; dt < 4; ++dt)
              orow[dt * 16 + col16] += g * (acc[mt][dt][r] + b2v[dt]);
          } else {
#pragma unroll
            for (int dt = 0; dt < 4; ++dt)
              orow[dt * 16 + col16] = g * (acc[mt][dt][r] + b2v[dt]);
          }
        }
      }
    }
  }
}

extern "C" void kernel_launch(void* const* d_in, const int* in_sizes, int n_in,
                              void* d_out, int out_size, void* d_ws, size_t ws_size,
                              hipStream_t stream) {
  const float* x     = (const float*)d_in[0];
  const float* noise = (const float*)d_in[1];
  const float* Wg    = (const float*)d_in[2];
  const float* bg    = (const float*)d_in[3];
  const float* Wn    = (const float*)d_in[4];
  const float* bn    = (const float*)d_in[5];
  const float* W1    = (const float*)d_in[6];
  const float* b1    = (const float*)d_in[7];
  const float* W2    = (const float*)d_in[8];
  const float* b2    = (const float*)d_in[9];
  float* out = (float*)d_out;
  char* ws = (char*)d_ws;

  // ws layout (ends at 203,229,184 B < 204,734,464 proven-good bound)
  u16*  w1t     = (u16*)(ws + 0x0000000);   // [E][H][D] bf16, 16 MB
  u16*  w2t     = (u16*)(ws + 0x1000000);   // [E][D][H] bf16, 16 MB
  u16*  xb      = (u16*)(ws + 0x2000000);   // [T][D] bf16, 32 MB
  int*  countsA = (int*)(ws + 0x4000000);   // [E]
  int*  countsB = (int*)(ws + 0x4000020);   // [E]
  float* wrt    = (float*)(ws + 0x4002000); // [16][512] f32 router weights, 32 KB
  int*  listsA  = (int*)(ws + 0x4010000);   // [E][CAP] int, 256 KB
  int*  listsB  = (int*)(ws + 0x4050000);
  float* gatesA = (float*)(ws + 0x4090000);
  float* gatesB = (float*)(ws + 0x40D0000);
  int*  topk_i  = (int*)(ws + 0x4110000);   // [T] int, 128 KB
  float* tg0    = (float*)(ws + 0x4130000); // [T]
  float* tg1    = (float*)(ws + 0x4150000); // [T]
  u16*  Hbuf    = (u16*)(ws + 0x4170000);   // [TT+128][HH] bf16 = 134.74 MB
  (void)ws_size;

  hipMemsetAsync(countsA, 0, 64, stream);   // covers countsA + countsB
  prep_router_w<<<16, 512, 0, stream>>>(Wg, Wn, wrt);
  transpose_bf16<<<dim3(HH / 32, DD / 32, EE), dim3(32, 8), 0, stream>>>(W1, w1t, DD, HH);
  transpose_bf16<<<dim3(DD / 32, HH / 32, EE), dim3(32, 8), 0, stream>>>(W2, w2t, HH, DD);
  router_topk<<<TT / 16, 256, 0, stream>>>(x, noise, wrt, bg, bn, xb, topk_i, tg0, tg1);
  router_bin<<<TT / 256, 256, 0, stream>>>(topk_i, tg0, tg1, countsA, countsB,
                                           listsA, listsB, gatesA, gatesB);

  // rank A (top-1 slots): plain store fully covers out
  pass1_gemm<<<8 * 16 * MS1, 256, 0, stream>>>(xb, w1t, b1, countsA, listsA, Hbuf);
  pass2_gemm<<<8 * 4 * MS2, 256, 0, stream>>>(Hbuf, w2t, b2, countsA, listsA, gatesA, out, 0);
  // rank B (top-2 slots): race-free read-add-write
  pass1_gemm<<<8 * 16 * MS1, 256, 0, stream>>>(xb, w1t, b1, countsB, listsB, Hbuf);
  pass2_gemm<<<8 * 4 * MS2, 256, 0, stream>>>(Hbuf, w2t, b2, countsB, listsB, gatesB, out, 1);
}

// Round 5
// 662.065 us; speedup vs baseline: 2.0978x; 1.1508x over previous
//
#include <hip/hip_runtime.h>

#define TT 32768   // B*S tokens
#define DD 512
#define HH 2048
#define EE 8
#define CAP 8192   // per-expert per-rank slot capacity (mean 4096, +68 sigma headroom)

typedef unsigned short u16;
typedef unsigned int u32;
typedef unsigned long long u64;
using short8  = __attribute__((ext_vector_type(8))) short;
using floatx4 = __attribute__((ext_vector_type(4))) float;

__device__ __forceinline__ u16 f2bf(float f) {
  unsigned u = __float_as_uint(f);
  u += 0x7FFFu + ((u >> 16) & 1u);   // RNE; inputs are finite
  return (u16)(u >> 16);
}

// async global->LDS, 16B per lane; lds dest is wave-uniform base + lane*16
__device__ __forceinline__ void gl2lds16(const u16* g, char* l) {
  __builtin_amdgcn_global_load_lds(
      (const __attribute__((address_space(1))) u32*)(const void*)g,
      (__attribute__((address_space(3))) u32*)(void*)l, 16, 0, 0);
}

// ------------- transpose fp32 [E][R][C] -> bf16 [E][C][R] -------------
__global__ void transpose_bf16(const float* __restrict__ in, u16* __restrict__ out, int R, int C) {
  __shared__ float tile[32][33];
  int e = blockIdx.z;
  const float* src = in + (size_t)e * R * C;
  u16* dst = out + (size_t)e * R * C;
  int tx = threadIdx.x, ty = threadIdx.y;
  int c0 = blockIdx.x * 32, r0 = blockIdx.y * 32;
#pragma unroll
  for (int i = 0; i < 32; i += 8)
    tile[ty + i][tx] = src[(size_t)(r0 + ty + i) * C + c0 + tx];
  __syncthreads();
#pragma unroll
  for (int i = 0; i < 32; i += 8)
    dst[(size_t)(c0 + ty + i) * R + r0 + tx] = f2bf(tile[tx][ty + i]);
}

// ---- router weight prep: wrt[16][512] f32; rows 0-7 = Wg^T, rows 8-15 = Wn^T ----
__global__ void prep_router_w(const float* __restrict__ Wg, const float* __restrict__ Wn,
                              float* __restrict__ wrt) {
  int c = blockIdx.x;          // 0..15
  int k = threadIdx.x;         // 0..511
  wrt[c * 512 + k] = (c < 8) ? Wg[k * 8 + c] : Wn[k * 8 + (c - 8)];
}

// ------- router pass 1 (v3): block = 16 tokens; thread (tok, col) owns one of the
// 16 router dots. BOTH x and wrt staged in LDS -> the dot loop does zero global
// loads (round-4 lesson: wrt in global thrashed the 32 KB L1 against the x-staging
// stream; every wr[k] load became an L2-latency stall -> VALUBusy 10%, 148 us).
// 516-float row stride: 16B-aligned b128 reads; x broadcasts across 16 lanes/token;
// w rows 2-way bank-aliased (free, m136). -------
__global__ __launch_bounds__(256)
void router_topk(const float* __restrict__ x, const float* __restrict__ noise,
                 const float* __restrict__ wrt, const float* __restrict__ bg,
                 const float* __restrict__ bn,
                 u16* __restrict__ xb, int* __restrict__ topk_i,
                 float* __restrict__ tg0, float* __restrict__ tg1) {
  __shared__ __align__(16) float xs[16 * 516];    // 33 KB
  __shared__ __align__(16) float wls[16 * 516];   // 33 KB
  const int tid = threadIdx.x;
  const int blk = blockIdx.x;                     // 16 tokens per block
  // stage wrt -> LDS (32 KB): 8 float4 per thread
  {
    const float4* wg4 = (const float4*)wrt;
#pragma unroll
    for (int j = 0; j < 8; ++j) {
      int L = tid + j * 256;               // 0..2047
      int c = L >> 7, c4 = L & 127;
      *(float4*)(wls + c * 516 + c4 * 4) = wg4[L];
    }
  }
  // stage x (16 rows) + fused bf16 emit (coalesced float4 / ushort4)
  const float4* xg = (const float4*)(x + (size_t)blk * 16 * DD);
  ushort4* xo = (ushort4*)(xb + (size_t)blk * 16 * DD);
#pragma unroll
  for (int j = 0; j < 8; ++j) {
    int L = tid + j * 256;                 // 0..2047 linear float4 index
    int tk = L >> 7, j4 = L & 127;
    float4 v = xg[L];
    *(float4*)(xs + tk * 516 + j4 * 4) = v;
    ushort4 o; o.x = f2bf(v.x); o.y = f2bf(v.y); o.z = f2bf(v.z); o.w = f2bf(v.w);
    xo[L] = o;
  }
  __syncthreads();
  const int tok = tid >> 4;        // 0..15
  const int col = tid & 15;        // 0..15: 0-7 Wg cols, 8-15 Wn cols
  const float4* xr = (const float4*)(xs + tok * 516);
  const float4* wr = (const float4*)(wls + col * 516);
  float acc = 0.f;
#pragma unroll 8
  for (int k = 0; k < 128; ++k) {
    float4 xv = xr[k];
    float4 wv = wr[k];
    acc += xv.x * wv.x + xv.y * wv.y + xv.z * wv.z + xv.w * wv.w;
  }
  const int t = blk * 16 + tok;
  float other = __shfl_xor(acc, 8);   // lanes col<8: acc=pg[col], other=pn[col]
  float noisy = -3.4e38f;
  if (col < 8) {
    float nl = other + bn[col];
    float sp = (nl > 20.f) ? nl : log1pf(expf(nl));
    noisy = acc + bg[col] + noise[(size_t)t * EE + col] * sp;
  }
  // top-1 over the 8 valid lanes (xor 1,2,4 stays inside each group of 8)
  float v = noisy; int vi = col;
#pragma unroll
  for (int off = 1; off <= 4; off <<= 1) {
    float ov = __shfl_xor(v, off);
    int   oi = __shfl_xor(vi, off);
    if (ov > v || (ov == v && oi < vi)) { v = ov; vi = oi; }
  }
  // top-2: mask out winner, reduce again
  float v2 = (col == vi) ? -3.4e38f : noisy;
  int vi2 = col;
#pragma unroll
  for (int off = 1; off <= 4; off <<= 1) {
    float ov = __shfl_xor(v2, off);
    int   oi = __shfl_xor(vi2, off);
    if (ov > v2 || (ov == v2 && oi < vi2)) { v2 = ov; vi2 = oi; }
  }
  if (col == 0) {
    float ed = expf(v2 - v);
    float inv = 1.f / (1.f + ed);
    topk_i[t] = vi | (vi2 << 8);
    tg0[t] = inv;
    tg1[t] = ed * inv;
  }
}

// ---- router pass 2: LDS double-histogram; 16 aggregated global atomics per 256 tokens.
// rank A = top-1 slot, rank B = top-2 slot (exactly one slot per token per rank). ----
__global__ void router_bin(const int* __restrict__ topk_i, const float* __restrict__ tg0,
                           const float* __restrict__ tg1,
                           int* __restrict__ countsA, int* __restrict__ countsB,
                           int* __restrict__ listsA, int* __restrict__ listsB,
                           float* __restrict__ gatesA, float* __restrict__ gatesB) {
  __shared__ int histA[EE], histB[EE], baseA[EE], baseB[EE];
  int t = blockIdx.x * 256 + threadIdx.x;
  if (threadIdx.x < EE) { histA[threadIdx.x] = 0; histB[threadIdx.x] = 0; }
  __syncthreads();
  int p = topk_i[t];
  int i0 = p & 255, i1 = p >> 8;
  int r0 = atomicAdd(&histA[i0], 1);
  int r1 = atomicAdd(&histB[i1], 1);
  __syncthreads();
  if (threadIdx.x < EE) {
    baseA[threadIdx.x] = atomicAdd(&countsA[threadIdx.x], histA[threadIdx.x]);
    baseB[threadIdx.x] = atomicAdd(&countsB[threadIdx.x], histB[threadIdx.x]);
  }
  __syncthreads();
  int s0 = baseA[i0] + r0, s1 = baseB[i1] + r1;
  if (s0 < CAP) { listsA[i0 * CAP + s0] = t; gatesA[i0 * CAP + s0] = tg0[t]; }
  if (s1 < CAP) { listsB[i1 * CAP + s1] = t; gatesB[i1 * CAP + s1] = tg1[t]; }
}

// ============ PASS 1: H = relu(X_gathered @ W1 + b1)  (bf16, full 2048-wide) ============
// 128x128 tile, BK=64, 4 waves x (64x64), XOR-swizzled 16B LDS chunks.
// blockIdx.x = e + 8*(nt + 16*ms); grid 1024 blocks = 4 blocks/CU (LDS 32KB allows 5;
// keep __launch_bounds__(256,2) -- the (256,4) VGPR squeeze was round-1's regression).
#define MS1 8
#define MS2 32
__global__ __launch_bounds__(256, 2)
void pass1_gemm(const u16* __restrict__ xb, const u16* __restrict__ w1t,
                const float* __restrict__ b1, const int* __restrict__ counts,
                const int* __restrict__ lists, u16* __restrict__ H) {
  __shared__ __align__(16) char lds[32768];
  char* ldsA = lds;           // W1^T tile [128 h][64 k]
  char* ldsB = lds + 16384;   // X tile    [128 m][64 k]
  const int e = blockIdx.x & 7;
  const int nt = (blockIdx.x >> 3) & 15;   // h-tile 0..15
  const int ms = blockIdx.x >> 7;          // m-seed 0..MS1-1
  int cnt = counts[e]; if (cnt > CAP) cnt = CAP;
  int eOff = 0;
#pragma unroll
  for (int j = 0; j < EE; ++j) {
    int cj = counts[j]; if (cj > CAP) cj = CAP;
    eOff += (j < e) ? cj : 0;
  }
  const int tid = threadIdx.x, lane = tid & 63, w = tid >> 6;
  const int col16 = lane & 15, quad = lane >> 4;
  const int hh = w & 1, mh = w >> 1;

  int rowi[4], kqi[4];
  const u16* wptr[4];
#pragma unroll
  for (int i = 0; i < 4; ++i) {
    int c = tid + i * 256;
    rowi[i] = c >> 3;
    kqi[i] = (c & 7) ^ (rowi[i] & 7);
    wptr[i] = w1t + (size_t)(e * HH + nt * 128 + rowi[i]) * DD + kqi[i] * 8;
  }

  for (int mtile = ms; mtile * 128 < cnt; mtile += MS1) {
    const u16* xptr[4];
#pragma unroll
    for (int i = 0; i < 4; ++i) {
      int idx = mtile * 128 + rowi[i];
      int tok = (idx < cnt) ? lists[e * CAP + idx] : 0;
      xptr[i] = xb + (size_t)tok * DD + kqi[i] * 8;
    }
    floatx4 acc[4][4];
#pragma unroll
    for (int a = 0; a < 4; ++a)
#pragma unroll
      for (int b = 0; b < 4; ++b) acc[a][b] = (floatx4){0.f, 0.f, 0.f, 0.f};

    for (int kc = 0; kc < DD / 64; ++kc) {      // K = 512, BK = 64
      __syncthreads();
#pragma unroll
      for (int i = 0; i < 4; ++i) {
        int off = (tid + i * 256) * 16;
        gl2lds16(wptr[i] + kc * 64, ldsA + off);
        gl2lds16(xptr[i] + kc * 64, ldsB + off);
      }
      __syncthreads();
#pragma unroll
      for (int ks = 0; ks < 2; ++ks) {
        short8 af[4], bf[4];
#pragma unroll
        for (int t4 = 0; t4 < 4; ++t4) {
          int rA = hh * 64 + t4 * 16 + col16;
          af[t4] = *(const short8*)(ldsA + (rA * 8 + ((ks * 4 + quad) ^ (rA & 7))) * 16);
          int rB = mh * 64 + t4 * 16 + col16;
          bf[t4] = *(const short8*)(ldsB + (rB * 8 + ((ks * 4 + quad) ^ (rB & 7))) * 16);
        }
#pragma unroll
        for (int ht = 0; ht < 4; ++ht)
#pragma unroll
          for (int mt = 0; mt < 4; ++mt)
            acc[ht][mt] = __builtin_amdgcn_mfma_f32_16x16x32_bf16(af[ht], bf[mt], acc[ht][mt], 0, 0, 0);
      }
    }
    // epilogue: +b1, relu, bf16 pack (4 consecutive h per lane -> b64 store)
#pragma unroll
    for (int ht = 0; ht < 4; ++ht) {
      int hloc = nt * 128 + hh * 64 + ht * 16 + quad * 4;
      float b1v[4];
#pragma unroll
      for (int r = 0; r < 4; ++r) b1v[r] = b1[e * HH + hloc + r];
#pragma unroll
      for (int mt = 0; mt < 4; ++mt) {
        int gm = mtile * 128 + mh * 64 + mt * 16 + col16;
        if (gm < cnt) {
          u64 pk = 0;
#pragma unroll
          for (int r = 0; r < 4; ++r) {
            float f = fmaxf(acc[ht][mt][r] + b1v[r], 0.f);
            pk |= (u64)f2bf(f) << (16 * r);
          }
          *(u64*)(H + (size_t)(eOff + gm) * HH + hloc) = pk;
        }
      }
    }
  }
}

// ============ PASS 2: out[tok] (=|+=) gate * (H @ W2 + b2), full K = 2048 ============
// rmw=0 (rank A / top-1): plain store, covers every token exactly once (no memset).
// rmw=1 (rank B / top-2): plain read-add-write; race-free (one slot per token).
__global__ __launch_bounds__(256, 2)
void pass2_gemm(const u16* __restrict__ H, const u16* __restrict__ w2t,
                const float* __restrict__ b2, const int* __restrict__ counts,
                const int* __restrict__ lists, const float* __restrict__ gates,
                float* __restrict__ out, int rmw) {
  __shared__ __align__(16) char lds[32768];
  char* ldsA = lds;           // H tile   [128 m][64 k]
  char* ldsB = lds + 16384;   // W2^T tile[128 d][64 k]
  const int e = blockIdx.x & 7;
  const int nt = (blockIdx.x >> 3) & 3;    // d-tile 0..3
  const int ms = blockIdx.x >> 5;          // m-seed 0..MS2-1
  int cnt = counts[e]; if (cnt > CAP) cnt = CAP;
  int eOff = 0;
#pragma unroll
  for (int j = 0; j < EE; ++j) {
    int cj = counts[j]; if (cj > CAP) cj = CAP;
    eOff += (j < e) ? cj : 0;
  }
  const int tid = threadIdx.x, lane = tid & 63, w = tid >> 6;
  const int col16 = lane & 15, quad = lane >> 4;
  const int mh = w & 1, dh = w >> 1;

  int rowi[4], kqi[4];
  const u16* wptr[4];
#pragma unroll
  for (int i = 0; i < 4; ++i) {
    int c = tid + i * 256;
    rowi[i] = c >> 3;
    kqi[i] = (c & 7) ^ (rowi[i] & 7);
    wptr[i] = w2t + (size_t)(e * DD + nt * 128 + rowi[i]) * HH + kqi[i] * 8;
  }

  for (int mtile = ms; mtile * 128 < cnt; mtile += MS2) {
    const u16* hptr[4];
#pragma unroll
    for (int i = 0; i < 4; ++i)
      hptr[i] = H + (size_t)(eOff + mtile * 128 + rowi[i]) * HH + kqi[i] * 8;  // pad rows exist

    floatx4 acc[4][4];
#pragma unroll
    for (int a = 0; a < 4; ++a)
#pragma unroll
      for (int b = 0; b < 4; ++b) acc[a][b] = (floatx4){0.f, 0.f, 0.f, 0.f};

    for (int kc = 0; kc < HH / 64; ++kc) {   // K = 2048, BK = 64
      __syncthreads();
#pragma unroll
      for (int i = 0; i < 4; ++i) {
        int off = (tid + i * 256) * 16;
        gl2lds16(hptr[i] + kc * 64, ldsA + off);
        gl2lds16(wptr[i] + kc * 64, ldsB + off);
      }
      __syncthreads();
#pragma unroll
      for (int ks = 0; ks < 2; ++ks) {
        short8 af[4], bf[4];
#pragma unroll
        for (int t4 = 0; t4 < 4; ++t4) {
          int rA = mh * 64 + t4 * 16 + col16;
          af[t4] = *(const short8*)(ldsA + (rA * 8 + ((ks * 4 + quad) ^ (rA & 7))) * 16);
          int rB = dh * 64 + t4 * 16 + col16;
          bf[t4] = *(const short8*)(ldsB + (rB * 8 + ((ks * 4 + quad) ^ (rB & 7))) * 16);
        }
#pragma unroll
        for (int mt = 0; mt < 4; ++mt)
#pragma unroll
          for (int dt = 0; dt < 4; ++dt)
            acc[mt][dt] = __builtin_amdgcn_mfma_f32_16x16x32_bf16(af[mt], bf[dt], acc[mt][dt], 0, 0, 0);
      }
    }
    // epilogue: out (=|+=) g * (acc + b2); plain stores, no atomics
    float b2v[4];
#pragma unroll
    for (int dt = 0; dt < 4; ++dt)
      b2v[dt] = b2[e * DD + nt * 128 + dh * 64 + dt * 16 + col16];
#pragma unroll
    for (int mt = 0; mt < 4; ++mt) {
#pragma unroll
      for (int r = 0; r < 4; ++r) {
        int idx = mtile * 128 + mh * 64 + mt * 16 + quad * 4 + r;
        if (idx < cnt) {
          int tok = lists[e * CAP + idx];
          float g = gates[e * CAP + idx];
          float* orow = out + (size_t)tok * DD + nt * 128 + dh * 64;
          if (rmw) {
#pragma unroll
            for (int dt = 0; dt < 4; ++dt)
              orow[dt * 16 + col16] += g * (acc[mt][dt][r] + b2v[dt]);
          } else {
#pragma unroll
            for (int dt = 0; dt < 4; ++dt)
              orow[dt * 16 + col16] = g * (acc[mt][dt][r] + b2v[dt]);
          }
        }
      }
    }
  }
}

extern "C" void kernel_launch(void* const* d_in, const int* in_sizes, int n_in,
                              void* d_out, int out_size, void* d_ws, size_t ws_size,
                              hipStream_t stream) {
  const float* x     = (const float*)d_in[0];
  const float* noise = (const float*)d_in[1];
  const float* Wg    = (const float*)d_in[2];
  const float* bg    = (const float*)d_in[3];
  const float* Wn    = (const float*)d_in[4];
  const float* bn    = (const float*)d_in[5];
  const float* W1    = (const float*)d_in[6];
  const float* b1    = (const float*)d_in[7];
  const float* W2    = (const float*)d_in[8];
  const float* b2    = (const float*)d_in[9];
  float* out = (float*)d_out;
  char* ws = (char*)d_ws;

  // ws layout (ends at 203,229,184 B < 204,734,464 proven-good bound)
  u16*  w1t     = (u16*)(ws + 0x0000000);   // [E][H][D] bf16, 16 MB
  u16*  w2t     = (u16*)(ws + 0x1000000);   // [E][D][H] bf16, 16 MB
  u16*  xb      = (u16*)(ws + 0x2000000);   // [T][D] bf16, 32 MB
  int*  countsA = (int*)(ws + 0x4000000);   // [E]
  int*  countsB = (int*)(ws + 0x4000020);   // [E]
  float* wrt    = (float*)(ws + 0x4002000); // [16][512] f32 router weights, 32 KB
  int*  listsA  = (int*)(ws + 0x4010000);   // [E][CAP] int, 256 KB
  int*  listsB  = (int*)(ws + 0x4050000);
  float* gatesA = (float*)(ws + 0x4090000);
  float* gatesB = (float*)(ws + 0x40D0000);
  int*  topk_i  = (int*)(ws + 0x4110000);   // [T] int, 128 KB
  float* tg0    = (float*)(ws + 0x4130000); // [T]
  float* tg1    = (float*)(ws + 0x4150000); // [T]
  u16*  Hbuf    = (u16*)(ws + 0x4170000);   // [TT+128][HH] bf16 = 134.74 MB
  (void)ws_size;

  hipMemsetAsync(countsA, 0, 64, stream);   // covers countsA + countsB
  prep_router_w<<<16, 512, 0, stream>>>(Wg, Wn, wrt);
  transpose_bf16<<<dim3(HH / 32, DD / 32, EE), dim3(32, 8), 0, stream>>>(W1, w1t, DD, HH);
  transpose_bf16<<<dim3(DD / 32, HH / 32, EE), dim3(32, 8), 0, stream>>>(W2, w2t, HH, DD);
  router_topk<<<TT / 16, 256, 0, stream>>>(x, noise, wrt, bg, bn, xb, topk_i, tg0, tg1);
  router_bin<<<TT / 256, 256, 0, stream>>>(topk_i, tg0, tg1, countsA, countsB,
                                           listsA, listsB, gatesA, gatesB);

  // rank A (top-1 slots): plain store fully covers out
  pass1_gemm<<<8 * 16 * MS1, 256, 0, stream>>>(xb, w1t, b1, countsA, listsA, Hbuf);
  pass2_gemm<<<8 * 4 * MS2, 256, 0, stream>>>(Hbuf, w2t, b2, countsA, listsA, gatesA, out, 0);
  // rank B (top-2 slots): race-free read-add-write
  pass1_gemm<<<8 * 16 * MS1, 256, 0, stream>>>(xb, w1t, b1, countsB, listsB, Hbuf);
  pass2_gemm<<<8 * 4 * MS2, 256, 0, stream>>>(Hbuf, w2t, b2, countsB, listsB, gatesB, out, 1);
}

// Round 6
// 623.071 us; speedup vs baseline: 2.2291x; 1.0626x over previous
//
#include <hip/hip_runtime.h>

#define TT 32768   // B*S tokens
#define DD 512
#define HH 2048
#define EE 8
#define CAP 8192   // per-expert per-rank slot capacity (mean 4096, +68 sigma headroom)

typedef unsigned short u16;
typedef unsigned int u32;
typedef unsigned long long u64;
using short8  = __attribute__((ext_vector_type(8))) short;
using floatx4 = __attribute__((ext_vector_type(4))) float;

__device__ __forceinline__ u16 f2bf(float f) {
  unsigned u = __float_as_uint(f);
  u += 0x7FFFu + ((u >> 16) & 1u);   // RNE; inputs are finite
  return (u16)(u >> 16);
}

// async global->LDS, 16B per lane; lds dest is wave-uniform base + lane*16
__device__ __forceinline__ void gl2lds16(const u16* g, char* l) {
  __builtin_amdgcn_global_load_lds(
      (const __attribute__((address_space(1))) u32*)(const void*)g,
      (__attribute__((address_space(3))) u32*)(void*)l, 16, 0, 0);
}

// ------------- transpose fp32 [E][R][C] -> bf16 [E][C][R] -------------
__global__ void transpose_bf16(const float* __restrict__ in, u16* __restrict__ out, int R, int C) {
  __shared__ float tile[32][33];
  int e = blockIdx.z;
  const float* src = in + (size_t)e * R * C;
  u16* dst = out + (size_t)e * R * C;
  int tx = threadIdx.x, ty = threadIdx.y;
  int c0 = blockIdx.x * 32, r0 = blockIdx.y * 32;
#pragma unroll
  for (int i = 0; i < 32; i += 8)
    tile[ty + i][tx] = src[(size_t)(r0 + ty + i) * C + c0 + tx];
  __syncthreads();
#pragma unroll
  for (int i = 0; i < 32; i += 8)
    dst[(size_t)(c0 + ty + i) * R + r0 + tx] = f2bf(tile[tx][ty + i]);
}

// ---- router weight prep: wrt[16][512] f32; rows 0-7 = Wg^T, rows 8-15 = Wn^T ----
__global__ void prep_router_w(const float* __restrict__ Wg, const float* __restrict__ Wn,
                              float* __restrict__ wrt) {
  int c = blockIdx.x;          // 0..15
  int k = threadIdx.x;         // 0..511
  wrt[c * 512 + k] = (c < 8) ? Wg[k * 8 + c] : Wn[k * 8 + (c - 8)];
}

// ------- router pass 1 (v3): block = 16 tokens; thread (tok, col) owns one of the
// 16 router dots. BOTH x and wrt staged in LDS -> the dot loop does zero global
// loads (round-4 lesson: wrt in global thrashed the 32 KB L1 against the x-staging
// stream; every wr[k] load became an L2-latency stall -> VALUBusy 10%, 148 us).
// Round 5: 148 -> <40 us. -------
__global__ __launch_bounds__(256)
void router_topk(const float* __restrict__ x, const float* __restrict__ noise,
                 const float* __restrict__ wrt, const float* __restrict__ bg,
                 const float* __restrict__ bn,
                 u16* __restrict__ xb, int* __restrict__ topk_i,
                 float* __restrict__ tg0, float* __restrict__ tg1) {
  __shared__ __align__(16) float xs[16 * 516];    // 33 KB
  __shared__ __align__(16) float wls[16 * 516];   // 33 KB
  const int tid = threadIdx.x;
  const int blk = blockIdx.x;                     // 16 tokens per block
  // stage wrt -> LDS (32 KB): 8 float4 per thread
  {
    const float4* wg4 = (const float4*)wrt;
#pragma unroll
    for (int j = 0; j < 8; ++j) {
      int L = tid + j * 256;               // 0..2047
      int c = L >> 7, c4 = L & 127;
      *(float4*)(wls + c * 516 + c4 * 4) = wg4[L];
    }
  }
  // stage x (16 rows) + fused bf16 emit (coalesced float4 / ushort4)
  const float4* xg = (const float4*)(x + (size_t)blk * 16 * DD);
  ushort4* xo = (ushort4*)(xb + (size_t)blk * 16 * DD);
#pragma unroll
  for (int j = 0; j < 8; ++j) {
    int L = tid + j * 256;                 // 0..2047 linear float4 index
    int tk = L >> 7, j4 = L & 127;
    float4 v = xg[L];
    *(float4*)(xs + tk * 516 + j4 * 4) = v;
    ushort4 o; o.x = f2bf(v.x); o.y = f2bf(v.y); o.z = f2bf(v.z); o.w = f2bf(v.w);
    xo[L] = o;
  }
  __syncthreads();
  const int tok = tid >> 4;        // 0..15
  const int col = tid & 15;        // 0..15: 0-7 Wg cols, 8-15 Wn cols
  const float4* xr = (const float4*)(xs + tok * 516);
  const float4* wr = (const float4*)(wls + col * 516);
  float acc = 0.f;
#pragma unroll 8
  for (int k = 0; k < 128; ++k) {
    float4 xv = xr[k];
    float4 wv = wr[k];
    acc += xv.x * wv.x + xv.y * wv.y + xv.z * wv.z + xv.w * wv.w;
  }
  const int t = blk * 16 + tok;
  float other = __shfl_xor(acc, 8);   // lanes col<8: acc=pg[col], other=pn[col]
  float noisy = -3.4e38f;
  if (col < 8) {
    float nl = other + bn[col];
    float sp = (nl > 20.f) ? nl : log1pf(expf(nl));
    noisy = acc + bg[col] + noise[(size_t)t * EE + col] * sp;
  }
  // top-1 over the 8 valid lanes (xor 1,2,4 stays inside each group of 8)
  float v = noisy; int vi = col;
#pragma unroll
  for (int off = 1; off <= 4; off <<= 1) {
    float ov = __shfl_xor(v, off);
    int   oi = __shfl_xor(vi, off);
    if (ov > v || (ov == v && oi < vi)) { v = ov; vi = oi; }
  }
  // top-2: mask out winner, reduce again
  float v2 = (col == vi) ? -3.4e38f : noisy;
  int vi2 = col;
#pragma unroll
  for (int off = 1; off <= 4; off <<= 1) {
    float ov = __shfl_xor(v2, off);
    int   oi = __shfl_xor(vi2, off);
    if (ov > v2 || (ov == v2 && oi < vi2)) { v2 = ov; vi2 = oi; }
  }
  if (col == 0) {
    float ed = expf(v2 - v);
    float inv = 1.f / (1.f + ed);
    topk_i[t] = vi | (vi2 << 8);
    tg0[t] = inv;
    tg1[t] = ed * inv;
  }
}

// ---- router pass 2: LDS double-histogram; 16 aggregated global atomics per 256 tokens.
// rank A = top-1 slot, rank B = top-2 slot (exactly one slot per token per rank). ----
__global__ void router_bin(const int* __restrict__ topk_i, const float* __restrict__ tg0,
                           const float* __restrict__ tg1,
                           int* __restrict__ countsA, int* __restrict__ countsB,
                           int* __restrict__ listsA, int* __restrict__ listsB,
                           float* __restrict__ gatesA, float* __restrict__ gatesB) {
  __shared__ int histA[EE], histB[EE], baseA[EE], baseB[EE];
  int t = blockIdx.x * 256 + threadIdx.x;
  if (threadIdx.x < EE) { histA[threadIdx.x] = 0; histB[threadIdx.x] = 0; }
  __syncthreads();
  int p = topk_i[t];
  int i0 = p & 255, i1 = p >> 8;
  int r0 = atomicAdd(&histA[i0], 1);
  int r1 = atomicAdd(&histB[i1], 1);
  __syncthreads();
  if (threadIdx.x < EE) {
    baseA[threadIdx.x] = atomicAdd(&countsA[threadIdx.x], histA[threadIdx.x]);
    baseB[threadIdx.x] = atomicAdd(&countsB[threadIdx.x], histB[threadIdx.x]);
  }
  __syncthreads();
  int s0 = baseA[i0] + r0, s1 = baseB[i1] + r1;
  if (s0 < CAP) { listsA[i0 * CAP + s0] = t; gatesA[i0 * CAP + s0] = tg0[t]; }
  if (s1 < CAP) { listsB[i1 * CAP + s1] = t; gatesB[i1 * CAP + s1] = tg1[t]; }
}

// ============ PASS 1: H = relu(X_gathered @ W1 + b1)  (bf16, full 2048-wide) ============
// 128x128 tile, BK=64, 4 waves x (64x64), XOR-swizzled 16B LDS chunks.
// Round 6: T3-minimum double-buffered prefetch (2x32 KB LDS). Per K-step:
// {issue gl2lds for kc+1 into buf^1} -> {ds_read+MFMA from buf} -> ONE __syncthreads
// (its implicit vmcnt(0) drain is the tile sync; loads had the whole MFMA phase).
// Round-5 counters: stage drain was fully serial (MfmaUtil 21%, occupancy 22%).
#define MS1 8
#define MS2 32
__global__ __launch_bounds__(256, 2)
void pass1_gemm(const u16* __restrict__ xb, const u16* __restrict__ w1t,
                const float* __restrict__ b1, const int* __restrict__ counts,
                const int* __restrict__ lists, u16* __restrict__ H) {
  __shared__ __align__(16) char lds[65536];      // 2 x {A 16K, B 16K}
  const int e = blockIdx.x & 7;
  const int nt = (blockIdx.x >> 3) & 15;   // h-tile 0..15
  const int ms = blockIdx.x >> 7;          // m-seed 0..MS1-1
  int cnt = counts[e]; if (cnt > CAP) cnt = CAP;
  int eOff = 0;
#pragma unroll
  for (int j = 0; j < EE; ++j) {
    int cj = counts[j]; if (cj > CAP) cj = CAP;
    eOff += (j < e) ? cj : 0;
  }
  const int tid = threadIdx.x, lane = tid & 63, w = tid >> 6;
  const int col16 = lane & 15, quad = lane >> 4;
  const int hh = w & 1, mh = w >> 1;

  int rowi[4], kqi[4];
  const u16* wptr[4];
#pragma unroll
  for (int i = 0; i < 4; ++i) {
    int c = tid + i * 256;
    rowi[i] = c >> 3;
    kqi[i] = (c & 7) ^ (rowi[i] & 7);
    wptr[i] = w1t + (size_t)(e * HH + nt * 128 + rowi[i]) * DD + kqi[i] * 8;
  }

  for (int mtile = ms; mtile * 128 < cnt; mtile += MS1) {
    const u16* xptr[4];
#pragma unroll
    for (int i = 0; i < 4; ++i) {
      int idx = mtile * 128 + rowi[i];
      int tok = (idx < cnt) ? lists[e * CAP + idx] : 0;
      xptr[i] = xb + (size_t)tok * DD + kqi[i] * 8;
    }
    floatx4 acc[4][4];
#pragma unroll
    for (int a = 0; a < 4; ++a)
#pragma unroll
      for (int b = 0; b < 4; ++b) acc[a][b] = (floatx4){0.f, 0.f, 0.f, 0.f};

    // prologue: stage kc=0 into buf 0
#pragma unroll
    for (int i = 0; i < 4; ++i) {
      int off = (tid + i * 256) * 16;
      gl2lds16(wptr[i], lds + off);
      gl2lds16(xptr[i], lds + 16384 + off);
    }
    __syncthreads();
    int cur = 0;
    for (int kc = 0; kc < DD / 64; ++kc) {      // K = 512, BK = 64
      if (kc < DD / 64 - 1) {                   // issue next-tile loads first
        char* nb = lds + (cur ^ 1) * 32768;
#pragma unroll
        for (int i = 0; i < 4; ++i) {
          int off = (tid + i * 256) * 16;
          gl2lds16(wptr[i] + (kc + 1) * 64, nb + off);
          gl2lds16(xptr[i] + (kc + 1) * 64, nb + 16384 + off);
        }
      }
      char* ldsA = lds + cur * 32768;
      char* ldsB = ldsA + 16384;
#pragma unroll
      for (int ks = 0; ks < 2; ++ks) {
        short8 af[4], bf[4];
#pragma unroll
        for (int t4 = 0; t4 < 4; ++t4) {
          int rA = hh * 64 + t4 * 16 + col16;
          af[t4] = *(const short8*)(ldsA + (rA * 8 + ((ks * 4 + quad) ^ (rA & 7))) * 16);
          int rB = mh * 64 + t4 * 16 + col16;
          bf[t4] = *(const short8*)(ldsB + (rB * 8 + ((ks * 4 + quad) ^ (rB & 7))) * 16);
        }
#pragma unroll
        for (int ht = 0; ht < 4; ++ht)
#pragma unroll
          for (int mt = 0; mt < 4; ++mt)
            acc[ht][mt] = __builtin_amdgcn_mfma_f32_16x16x32_bf16(af[ht], bf[mt], acc[ht][mt], 0, 0, 0);
      }
      __syncthreads();     // one barrier/K-step: drains next-tile loads + read fence
      cur ^= 1;
    }
    // epilogue: +b1, relu, bf16 pack (4 consecutive h per lane -> b64 store)
#pragma unroll
    for (int ht = 0; ht < 4; ++ht) {
      int hloc = nt * 128 + hh * 64 + ht * 16 + quad * 4;
      float b1v[4];
#pragma unroll
      for (int r = 0; r < 4; ++r) b1v[r] = b1[e * HH + hloc + r];
#pragma unroll
      for (int mt = 0; mt < 4; ++mt) {
        int gm = mtile * 128 + mh * 64 + mt * 16 + col16;
        if (gm < cnt) {
          u64 pk = 0;
#pragma unroll
          for (int r = 0; r < 4; ++r) {
            float f = fmaxf(acc[ht][mt][r] + b1v[r], 0.f);
            pk |= (u64)f2bf(f) << (16 * r);
          }
          *(u64*)(H + (size_t)(eOff + gm) * HH + hloc) = pk;
        }
      }
    }
  }
}

// ============ PASS 2: out[tok] (=|+=) gate * (H @ W2 + b2), full K = 2048 ============
// rmw=0 (rank A / top-1): plain store, covers every token exactly once (no memset).
// rmw=1 (rank B / top-2): plain read-add-write; race-free (one slot per token).
// Round 6: same double-buffered prefetch as pass1 (32 steady-state K-steps).
__global__ __launch_bounds__(256, 2)
void pass2_gemm(const u16* __restrict__ H, const u16* __restrict__ w2t,
                const float* __restrict__ b2, const int* __restrict__ counts,
                const int* __restrict__ lists, const float* __restrict__ gates,
                float* __restrict__ out, int rmw) {
  __shared__ __align__(16) char lds[65536];      // 2 x {A 16K, B 16K}
  const int e = blockIdx.x & 7;
  const int nt = (blockIdx.x >> 3) & 3;    // d-tile 0..3
  const int ms = blockIdx.x >> 5;          // m-seed 0..MS2-1
  int cnt = counts[e]; if (cnt > CAP) cnt = CAP;
  int eOff = 0;
#pragma unroll
  for (int j = 0; j < EE; ++j) {
    int cj = counts[j]; if (cj > CAP) cj = CAP;
    eOff += (j < e) ? cj : 0;
  }
  const int tid = threadIdx.x, lane = tid & 63, w = tid >> 6;
  const int col16 = lane & 15, quad = lane >> 4;
  const int mh = w & 1, dh = w >> 1;

  int rowi[4], kqi[4];
  const u16* wptr[4];
#pragma unroll
  for (int i = 0; i < 4; ++i) {
    int c = tid + i * 256;
    rowi[i] = c >> 3;
    kqi[i] = (c & 7) ^ (rowi[i] & 7);
    wptr[i] = w2t + (size_t)(e * DD + nt * 128 + rowi[i]) * HH + kqi[i] * 8;
  }

  for (int mtile = ms; mtile * 128 < cnt; mtile += MS2) {
    const u16* hptr[4];
#pragma unroll
    for (int i = 0; i < 4; ++i)
      hptr[i] = H + (size_t)(eOff + mtile * 128 + rowi[i]) * HH + kqi[i] * 8;  // pad rows exist

    floatx4 acc[4][4];
#pragma unroll
    for (int a = 0; a < 4; ++a)
#pragma unroll
      for (int b = 0; b < 4; ++b) acc[a][b] = (floatx4){0.f, 0.f, 0.f, 0.f};

    // prologue: stage kc=0 into buf 0
#pragma unroll
    for (int i = 0; i < 4; ++i) {
      int off = (tid + i * 256) * 16;
      gl2lds16(hptr[i], lds + off);
      gl2lds16(wptr[i], lds + 16384 + off);
    }
    __syncthreads();
    int cur = 0;
    for (int kc = 0; kc < HH / 64; ++kc) {   // K = 2048, BK = 64
      if (kc < HH / 64 - 1) {                // issue next-tile loads first
        char* nb = lds + (cur ^ 1) * 32768;
#pragma unroll
        for (int i = 0; i < 4; ++i) {
          int off = (tid + i * 256) * 16;
          gl2lds16(hptr[i] + (kc + 1) * 64, nb + off);
          gl2lds16(wptr[i] + (kc + 1) * 64, nb + 16384 + off);
        }
      }
      char* ldsA = lds + cur * 32768;
      char* ldsB = ldsA + 16384;
#pragma unroll
      for (int ks = 0; ks < 2; ++ks) {
        short8 af[4], bf[4];
#pragma unroll
        for (int t4 = 0; t4 < 4; ++t4) {
          int rA = mh * 64 + t4 * 16 + col16;
          af[t4] = *(const short8*)(ldsA + (rA * 8 + ((ks * 4 + quad) ^ (rA & 7))) * 16);
          int rB = dh * 64 + t4 * 16 + col16;
          bf[t4] = *(const short8*)(ldsB + (rB * 8 + ((ks * 4 + quad) ^ (rB & 7))) * 16);
        }
#pragma unroll
        for (int mt = 0; mt < 4; ++mt)
#pragma unroll
          for (int dt = 0; dt < 4; ++dt)
            acc[mt][dt] = __builtin_amdgcn_mfma_f32_16x16x32_bf16(af[mt], bf[dt], acc[mt][dt], 0, 0, 0);
      }
      __syncthreads();     // one barrier/K-step
      cur ^= 1;
    }
    // epilogue: out (=|+=) g * (acc + b2); plain stores, no atomics
    float b2v[4];
#pragma unroll
    for (int dt = 0; dt < 4; ++dt)
      b2v[dt] = b2[e * DD + nt * 128 + dh * 64 + dt * 16 + col16];
#pragma unroll
    for (int mt = 0; mt < 4; ++mt) {
#pragma unroll
      for (int r = 0; r < 4; ++r) {
        int idx = mtile * 128 + mh * 64 + mt * 16 + quad * 4 + r;
        if (idx < cnt) {
          int tok = lists[e * CAP + idx];
          float g = gates[e * CAP + idx];
          float* orow = out + (size_t)tok * DD + nt * 128 + dh * 64;
          if (rmw) {
#pragma unroll
            for (int dt = 0; dt < 4; ++dt)
              orow[dt * 16 + col16] += g * (acc[mt][dt][r] + b2v[dt]);
          } else {
#pragma unroll
            for (int dt = 0; dt < 4; ++dt)
              orow[dt * 16 + col16] = g * (acc[mt][dt][r] + b2v[dt]);
          }
        }
      }
    }
  }
}

extern "C" void kernel_launch(void* const* d_in, const int* in_sizes, int n_in,
                              void* d_out, int out_size, void* d_ws, size_t ws_size,
                              hipStream_t stream) {
  const float* x     = (const float*)d_in[0];
  const float* noise = (const float*)d_in[1];
  const float* Wg    = (const float*)d_in[2];
  const float* bg    = (const float*)d_in[3];
  const float* Wn    = (const float*)d_in[4];
  const float* bn    = (const float*)d_in[5];
  const float* W1    = (const float*)d_in[6];
  const float* b1    = (const float*)d_in[7];
  const float* W2    = (const float*)d_in[8];
  const float* b2    = (const float*)d_in[9];
  float* out = (float*)d_out;
  char* ws = (char*)d_ws;

  // ws layout (ends at 203,229,184 B < 204,734,464 proven-good bound)
  u16*  w1t     = (u16*)(ws + 0x0000000);   // [E][H][D] bf16, 16 MB
  u16*  w2t     = (u16*)(ws + 0x1000000);   // [E][D][H] bf16, 16 MB
  u16*  xb      = (u16*)(ws + 0x2000000);   // [T][D] bf16, 32 MB
  int*  countsA = (int*)(ws + 0x4000000);   // [E]
  int*  countsB = (int*)(ws + 0x4000020);   // [E]
  float* wrt    = (float*)(ws + 0x4002000); // [16][512] f32 router weights, 32 KB
  int*  listsA  = (int*)(ws + 0x4010000);   // [E][CAP] int, 256 KB
  int*  listsB  = (int*)(ws + 0x4050000);
  float* gatesA = (float*)(ws + 0x4090000);
  float* gatesB = (float*)(ws + 0x40D0000);
  int*  topk_i  = (int*)(ws + 0x4110000);   // [T] int, 128 KB
  float* tg0    = (float*)(ws + 0x4130000); // [T]
  float* tg1    = (float*)(ws + 0x4150000); // [T]
  u16*  Hbuf    = (u16*)(ws + 0x4170000);   // [TT+128][HH] bf16 = 134.74 MB
  (void)ws_size;

  hipMemsetAsync(countsA, 0, 64, stream);   // covers countsA + countsB
  prep_router_w<<<16, 512, 0, stream>>>(Wg, Wn, wrt);
  transpose_bf16<<<dim3(HH / 32, DD / 32, EE), dim3(32, 8), 0, stream>>>(W1, w1t, DD, HH);
  transpose_bf16<<<dim3(DD / 32, HH / 32, EE), dim3(32, 8), 0, stream>>>(W2, w2t, HH, DD);
  router_topk<<<TT / 16, 256, 0, stream>>>(x, noise, wrt, bg, bn, xb, topk_i, tg0, tg1);
  router_bin<<<TT / 256, 256, 0, stream>>>(topk_i, tg0, tg1, countsA, countsB,
                                           listsA, listsB, gatesA, gatesB);

  // rank A (top-1 slots): plain store fully covers out
  pass1_gemm<<<8 * 16 * MS1, 256, 0, stream>>>(xb, w1t, b1, countsA, listsA, Hbuf);
  pass2_gemm<<<8 * 4 * MS2, 256, 0, stream>>>(Hbuf, w2t, b2, countsA, listsA, gatesA, out, 0);
  // rank B (top-2 slots): race-free read-add-write
  pass1_gemm<<<8 * 16 * MS1, 256, 0, stream>>>(xb, w1t, b1, countsB, listsB, Hbuf);
  pass2_gemm<<<8 * 4 * MS2, 256, 0, stream>>>(Hbuf, w2t, b2, countsB, listsB, gatesB, out, 1);
}